// Round 15
// baseline (419.152 us; speedup 1.0000x reference)
//
#include <hip/hip_runtime.h>
#include <cstdint>

// GAT 2-layer: N=50000, E=800000.
// Layer 1 via linearity: aggregate x (256B bf16 rows), then batched per-head
// MFMA GEMM. Agg kernels: 4 nodes per wave (4 independent gather chains),
// no-max softmax (exp(e) direct, 1/z applied at end).
#define NN 50000
#define NE 800000

typedef short bf16x8 __attribute__((ext_vector_type(8)));
typedef float f32x4 __attribute__((ext_vector_type(4)));
typedef float f32x2 __attribute__((ext_vector_type(2)));

__device__ __forceinline__ float lrelu(float x) { return x > 0.f ? x : 0.2f * x; }
__device__ __forceinline__ float elu(float x) { return x > 0.f ? x : __expf(x) - 1.f; }
__device__ __forceinline__ unsigned short f2bf(float f) {
  unsigned u = __float_as_uint(f);
  unsigned r = (u + 0x7FFFu + ((u >> 16) & 1u)) >> 16;   // RNE
  return (unsigned short)r;
}
__device__ __forceinline__ f32x2 fma2(f32x2 a, f32x2 b, f32x2 c) {
#if __has_builtin(__builtin_elementwise_fma)
  return __builtin_elementwise_fma(a, b, c);
#else
  f32x2 r; r[0] = fmaf(a[0], b[0], c[0]); r[1] = fmaf(a[1], b[1], c[1]); return r;
#endif
}

// all-static accumulator block for one node (rule #20: named members only)
struct Acc8 {
  f32x2 a00, a01, a10, a11, a20, a21, a30, a31;
};

// ===================== prep (fused cvt_x + w-transposes + walb + hist) ======
__global__ __launch_bounds__(256)
void prep_all_kernel(const float* __restrict__ x, unsigned short* __restrict__ xb,
                     const float* __restrict__ W1, const float* __restrict__ W2,
                     const float* __restrict__ al, const float* __restrict__ ar,
                     unsigned short* __restrict__ w1t, unsigned short* __restrict__ w2t,
                     unsigned short* __restrict__ walb,
                     const int* __restrict__ dst, int* __restrict__ cnt) {
  int idx = blockIdx.x * 256 + threadIdx.x;
  if (idx < 800000) {                          // cvt_x: 8 elems each
    float4 a = *(const float4*)(x + (size_t)idx * 8);
    float4 b = *(const float4*)(x + (size_t)idx * 8 + 4);
    unsigned short us[8] = { f2bf(a.x), f2bf(a.y), f2bf(a.z), f2bf(a.w),
                             f2bf(b.x), f2bf(b.y), f2bf(b.z), f2bf(b.w) };
    *(uint4*)(xb + (size_t)idx * 8) = *(const uint4*)us;
  } else if (idx < 865536) {                   // W1 -> w1t [512][128]
    int t = idx - 800000;
    int k = t >> 9, c = t & 511;
    w1t[(size_t)c * 128 + k] = f2bf(W1[t]);
  } else if (idx < 898304) {                   // W2 -> w2t [64][512]
    int t = idx - 865536;
    int k = t >> 6, c = t & 63;
    w2t[(size_t)c * 512 + k] = f2bf(W2[t]);
  } else if (idx < 900352) {                   // walb [16][128]
    int t = idx - 898304;
    int k = t >> 4, o = t & 15, h = o & 7;
    const float* a = (o < 8) ? al : ar;
    float s = 0.f;
    #pragma unroll 8
    for (int d = 0; d < 64; ++d)
      s += W1[(size_t)k * 512 + h * 64 + d] * a[h * 64 + d];
    walb[o * 128 + k] = f2bf(s);
  } else if (idx < 1700352) {                  // hist
    int e = idx - 900352;
    atomicAdd(&cnt[dst[e]], 1);
  }
}

// ===== eler: el1/er1 [N,8] = xb @ walb^T via MFMA, 16 nodes/wave ============
__global__ __launch_bounds__(256)
void eler_kernel(const unsigned short* __restrict__ xb,    // [NN][128]
                 const unsigned short* __restrict__ walb,  // [16][128]
                 float* __restrict__ el, float* __restrict__ er) {
  int wv = threadIdx.x >> 6, lane = threadIdx.x & 63;
  int row0 = blockIdx.x * 64 + wv * 16;
  const int l15 = lane & 15, kg = lane >> 4;
  f32x4 c = {0.f, 0.f, 0.f, 0.f};
  #pragma unroll
  for (int ks = 0; ks < 4; ++ks) {
    bf16x8 a = {};
    int row = row0 + l15;
    if (row < NN) a = *(const bf16x8*)(xb + (size_t)row * 128 + ks * 32 + kg * 8);
    bf16x8 b = *(const bf16x8*)(walb + (size_t)l15 * 128 + ks * 32 + kg * 8);
    c = __builtin_amdgcn_mfma_f32_16x16x32_bf16(a, b, c, 0, 0, 0);
  }
  #pragma unroll
  for (int r = 0; r < 4; ++r) {
    int row = row0 + kg * 4 + r;
    if (row < NN) {
      if (l15 < 8) el[(size_t)row * 8 + l15] = c[r];
      else         er[(size_t)row * 8 + (l15 - 8)] = c[r];
    }
  }
}

// ===================== CSR scan + scatter ====================================
__global__ __launch_bounds__(1024)
void scan_kernel(const int* __restrict__ cnt, int* __restrict__ rowptr, int N) {
  __shared__ int sums[1024];
  int t = threadIdx.x;
  const int CH = (N + 1023) / 1024;
  int s0 = t * CH, s1 = s0 + CH; if (s1 > N) s1 = N;
  int s = 0;
  for (int i = s0; i < s1; ++i) s += cnt[i];
  sums[t] = s;
  __syncthreads();
  for (int d = 1; d < 1024; d <<= 1) {
    int v = sums[t];
    int u = (t >= d) ? sums[t - d] : 0;
    __syncthreads();
    sums[t] = v + u;
    __syncthreads();
  }
  int run = (t == 0) ? 0 : sums[t - 1];
  for (int i = s0; i < s1; ++i) { rowptr[i] = run; run += cnt[i]; }
  if (t == 1023) rowptr[N] = sums[1023];
}

__global__ void scatter_kernel(const int* __restrict__ dst, const int* __restrict__ src,
                               const int* __restrict__ rowptr, int* __restrict__ fill,
                               int* __restrict__ srcs, int E) {
  int e = blockIdx.x * 256 + threadIdx.x;
  if (e >= E) return;
  int d = dst[e];
  int pos = atomicAdd(&fill[d], 1);
  srcs[rowptr[d] + pos] = src[e];
}

// ==== aggx: xagg[n,h,:] = sum_e alpha_e,h * xb[src_e,:]; 4 nodes per wave ====
__global__ __launch_bounds__(256)
void aggx_kernel(const unsigned short* __restrict__ xb,
                 const float* __restrict__ el, const float* __restrict__ er,
                 const int* __restrict__ srcs, const int* __restrict__ rowptr,
                 unsigned short* __restrict__ xagg, int N) {
  __shared__ float wlds[4][4][64 * 8];     // 32 KB
  __shared__ int slds[4][4][64];           // 4 KB
  __shared__ float mzlds[4][4][8];         // 0.5 KB
  int wv = threadIdx.x >> 6;
  int lane = threadIdx.x & 63;
  const int myh = lane >> 3, j = lane & 7;
  int nb = blockIdx.x * 16 + wv * 4;
  int n0 = nb, n1 = nb + 1, n2 = nb + 2, n3 = nb + 3;
  int p00 = 0, d0 = 0, p01 = 0, d1 = 0, p02 = 0, d2 = 0, p03 = 0, d3 = 0;
  if (n0 < N) { p00 = rowptr[n0]; d0 = rowptr[n0 + 1] - p00; }
  if (n1 < N) { p01 = rowptr[n1]; d1 = rowptr[n1 + 1] - p01; }
  if (n2 < N) { p02 = rowptr[n2]; d2 = rowptr[n2 + 1] - p02; }
  if (n3 < N) { p03 = rowptr[n3]; d3 = rowptr[n3 + 1] - p03; }
  float* wl0 = wlds[wv][0]; float* wl1 = wlds[wv][1];
  float* wl2 = wlds[wv][2]; float* wl3 = wlds[wv][3];
  int* sd0 = slds[wv][0]; int* sd1 = slds[wv][1];
  int* sd2 = slds[wv][2]; int* sd3 = slds[wv][3];
  float* mz0 = mzlds[wv][0]; float* mz1 = mzlds[wv][1];
  float* mz2 = mzlds[wv][2]; float* mz3 = mzlds[wv][3];

  auto store_out = [&](Acc8& A, int n, const float* mzp, int d) {
    if (n >= N) return;
    if (d > 0) {
      float iz[8];
      #pragma unroll
      for (int h = 0; h < 8; ++h) iz[h] = mzp[h];
      f32x2 s01, s23, s45, s67;
      s01[0] = iz[0]; s01[1] = iz[1]; s23[0] = iz[2]; s23[1] = iz[3];
      s45[0] = iz[4]; s45[1] = iz[5]; s67[0] = iz[6]; s67[1] = iz[7];
      A.a00 *= s01; A.a01 *= s01; A.a10 *= s23; A.a11 *= s23;
      A.a20 *= s45; A.a21 *= s45; A.a30 *= s67; A.a31 *= s67;
    }
    unsigned short* op = xagg + (size_t)n * 1024;
    unsigned pk;
    pk = (unsigned)f2bf(A.a00[0]) | ((unsigned)f2bf(A.a01[0]) << 16);
    *(unsigned*)(op + 0 * 128 + lane * 2) = pk;
    pk = (unsigned)f2bf(A.a00[1]) | ((unsigned)f2bf(A.a01[1]) << 16);
    *(unsigned*)(op + 1 * 128 + lane * 2) = pk;
    pk = (unsigned)f2bf(A.a10[0]) | ((unsigned)f2bf(A.a11[0]) << 16);
    *(unsigned*)(op + 2 * 128 + lane * 2) = pk;
    pk = (unsigned)f2bf(A.a10[1]) | ((unsigned)f2bf(A.a11[1]) << 16);
    *(unsigned*)(op + 3 * 128 + lane * 2) = pk;
    pk = (unsigned)f2bf(A.a20[0]) | ((unsigned)f2bf(A.a21[0]) << 16);
    *(unsigned*)(op + 4 * 128 + lane * 2) = pk;
    pk = (unsigned)f2bf(A.a20[1]) | ((unsigned)f2bf(A.a21[1]) << 16);
    *(unsigned*)(op + 5 * 128 + lane * 2) = pk;
    pk = (unsigned)f2bf(A.a30[0]) | ((unsigned)f2bf(A.a31[0]) << 16);
    *(unsigned*)(op + 6 * 128 + lane * 2) = pk;
    pk = (unsigned)f2bf(A.a30[1]) | ((unsigned)f2bf(A.a31[1]) << 16);
    *(unsigned*)(op + 7 * 128 + lane * 2) = pk;
  };

  if (d0 > 64 || d1 > 64 || d2 > 64 || d3 > 64) {
    // ---- rare fallback: whole-wave per node, 3-pass chunked with max ----
    for (int q = 0; q < 4; ++q) {
      int n = q == 0 ? n0 : q == 1 ? n1 : q == 2 ? n2 : n3;
      if (n >= N) continue;
      int p0 = q == 0 ? p00 : q == 1 ? p01 : q == 2 ? p02 : p03;
      int deg = q == 0 ? d0 : q == 1 ? d1 : q == 2 ? d2 : d3;
      Acc8 A;
      A.a00 = {0.f, 0.f}; A.a01 = A.a00; A.a10 = A.a00; A.a11 = A.a00;
      A.a20 = A.a00; A.a21 = A.a00; A.a30 = A.a00; A.a31 = A.a00;
      if (deg > 0) {
        int p1 = p0 + deg;
        float er8[8];
        *(float4*)&er8[0] = *(const float4*)(er + (size_t)n * 8);
        *(float4*)&er8[4] = *(const float4*)(er + (size_t)n * 8 + 4);
        float erh = er8[0];
        #pragma unroll
        for (int h = 1; h < 8; ++h) erh = (myh == h) ? er8[h] : erh;
        float m = -3.4e38f;
        for (int i = p0 + j; i < p1; i += 8)
          m = fmaxf(m, lrelu(el[(size_t)srcs[i] * 8 + myh] + erh));
        m = fmaxf(m, __shfl_xor(m, 1));
        m = fmaxf(m, __shfl_xor(m, 2));
        m = fmaxf(m, __shfl_xor(m, 4));
        float z = 0.f;
        for (int i = p0 + j; i < p1; i += 8)
          z += __expf(lrelu(el[(size_t)srcs[i] * 8 + myh] + erh) - m);
        z += __shfl_xor(z, 1); z += __shfl_xor(z, 2); z += __shfl_xor(z, 4);
        if (j == 0) { mz0[myh] = m; mz1[myh] = 1.f / z; }
        asm volatile("s_waitcnt lgkmcnt(0)" ::: "memory");
        float m8[8];
        #pragma unroll
        for (int h = 0; h < 8; ++h) m8[h] = mz0[h];
        for (int c0 = p0; c0 < p1; c0 += 64) {
          int cnt = min(64, p1 - c0);
          if (lane < cnt) {
            int s = srcs[c0 + lane];
            sd0[lane] = s;
            float elr[8];
            *(float4*)&elr[0] = *(const float4*)(el + (size_t)s * 8);
            *(float4*)&elr[4] = *(const float4*)(el + (size_t)s * 8 + 4);
            #pragma unroll
            for (int h = 0; h < 8; ++h)
              wl0[lane * 8 + h] = __expf(lrelu(elr[h] + er8[h]) - m8[h]);
          }
          asm volatile("s_waitcnt lgkmcnt(0)" ::: "memory");
          for (int i = 0; i < cnt; ++i) {
            int s2 = sd0[i];
            unsigned u = *(const unsigned*)(xb + (size_t)s2 * 128 + lane * 2);
            float4 wa = *(const float4*)&wl0[i * 8];
            float4 wb = *(const float4*)&wl0[i * 8 + 4];
            f32x2 lod, hid;
            lod[0] = lod[1] = __uint_as_float(u << 16);
            hid[0] = hid[1] = __uint_as_float(u & 0xFFFF0000u);
            f32x2 w01, w23, w45, w67;
            w01[0] = wa.x; w01[1] = wa.y; w23[0] = wa.z; w23[1] = wa.w;
            w45[0] = wb.x; w45[1] = wb.y; w67[0] = wb.z; w67[1] = wb.w;
            A.a00 = fma2(w01, lod, A.a00); A.a01 = fma2(w01, hid, A.a01);
            A.a10 = fma2(w23, lod, A.a10); A.a11 = fma2(w23, hid, A.a11);
            A.a20 = fma2(w45, lod, A.a20); A.a21 = fma2(w45, hid, A.a21);
            A.a30 = fma2(w67, lod, A.a30); A.a31 = fma2(w67, hid, A.a31);
          }
          asm volatile("s_waitcnt lgkmcnt(0)" ::: "memory");
        }
      }
      store_out(A, n, mz1, deg);
    }
    return;
  }

  // ---- fast path: no-max softmax, 4 nodes interleaved ----
  auto stage = [&](int n, int p0, int d, float* wl, int* sd) {
    if (n >= N || d <= 0) return;
    float er8[8];
    *(float4*)&er8[0] = *(const float4*)(er + (size_t)n * 8);
    *(float4*)&er8[4] = *(const float4*)(er + (size_t)n * 8 + 4);
    float w8[8] = {0.f, 0.f, 0.f, 0.f, 0.f, 0.f, 0.f, 0.f};
    if (lane < d) {
      int s = srcs[p0 + lane];
      sd[lane] = s;
      float elr[8];
      *(float4*)&elr[0] = *(const float4*)(el + (size_t)s * 8);
      *(float4*)&elr[4] = *(const float4*)(el + (size_t)s * 8 + 4);
      #pragma unroll
      for (int h = 0; h < 8; ++h) w8[h] = __expf(lrelu(elr[h] + er8[h]));
    }
    #pragma unroll
    for (int h = 0; h < 8; ++h) wl[lane * 8 + h] = w8[h];
  };
  stage(n0, p00, d0, wl0, sd0);
  stage(n1, p01, d1, wl1, sd1);
  stage(n2, p02, d2, wl2, sd2);
  stage(n3, p03, d3, wl3, sd3);
  asm volatile("s_waitcnt lgkmcnt(0)" ::: "memory");
  auto zred = [&](int n, int d, const float* wl, float* mzp) {
    if (n >= N || d <= 0) return;
    float z = 0.f;
    #pragma unroll
    for (int t2 = 0; t2 < 8; ++t2) z += wl[(t2 * 8 + j) * 8 + myh];
    z += __shfl_xor(z, 1); z += __shfl_xor(z, 2); z += __shfl_xor(z, 4);
    if (j == 0) mzp[myh] = 1.f / z;
  };
  zred(n0, d0, wl0, mz0);
  zred(n1, d1, wl1, mz1);
  zred(n2, d2, wl2, mz2);
  zred(n3, d3, wl3, mz3);
  asm volatile("s_waitcnt lgkmcnt(0)" ::: "memory");

  Acc8 A0, A1, A2, A3;
  A0.a00 = {0.f, 0.f}; A0.a01 = A0.a00; A0.a10 = A0.a00; A0.a11 = A0.a00;
  A0.a20 = A0.a00; A0.a21 = A0.a00; A0.a30 = A0.a00; A0.a31 = A0.a00;
  A1 = A0; A2 = A0; A3 = A0;
  auto step = [&](Acc8& A, const int* sd, const float* wl, int i) {
    int s2 = sd[i];
    unsigned u = *(const unsigned*)(xb + (size_t)s2 * 128 + lane * 2);
    float4 wa = *(const float4*)&wl[i * 8];
    float4 wb = *(const float4*)&wl[i * 8 + 4];
    f32x2 lod, hid;
    lod[0] = lod[1] = __uint_as_float(u << 16);
    hid[0] = hid[1] = __uint_as_float(u & 0xFFFF0000u);
    f32x2 w01, w23, w45, w67;
    w01[0] = wa.x; w01[1] = wa.y; w23[0] = wa.z; w23[1] = wa.w;
    w45[0] = wb.x; w45[1] = wb.y; w67[0] = wb.z; w67[1] = wb.w;
    A.a00 = fma2(w01, lod, A.a00); A.a01 = fma2(w01, hid, A.a01);
    A.a10 = fma2(w23, lod, A.a10); A.a11 = fma2(w23, hid, A.a11);
    A.a20 = fma2(w45, lod, A.a20); A.a21 = fma2(w45, hid, A.a21);
    A.a30 = fma2(w67, lod, A.a30); A.a31 = fma2(w67, hid, A.a31);
  };
  int dmax = max(max(d0, d1), max(d2, d3));
  for (int i = 0; i < dmax; ++i) {
    if (i < d0) step(A0, sd0, wl0, i);
    if (i < d1) step(A1, sd1, wl1, i);
    if (i < d2) step(A2, sd2, wl2, i);
    if (i < d3) step(A3, sd3, wl3, i);
  }
  store_out(A0, n0, mz0, d0);
  store_out(A1, n1, mz1, d1);
  store_out(A2, n2, mz2, d2);
  store_out(A3, n3, mz3, d3);
}

// ===== gemm1b: out1e[:, h*64:+64] = elu(xagg[:,h,:] @ W1_h + b1_h), bf16 =====
__global__ __launch_bounds__(256)
void gemm1b_mfma(const unsigned short* __restrict__ A,     // xagg [NN][8][128]
                 const unsigned short* __restrict__ w1t,   // [512][128]
                 const float* __restrict__ bias,           // b1 [512]
                 unsigned short* __restrict__ out) {       // out1e [NN][512]
  __shared__ unsigned short As[128][72];
  __shared__ unsigned short Bs[64][72];
  const int t = threadIdx.x, lane = t & 63, wid = t >> 6;
  const int h = blockIdx.y;
  const int row0 = blockIdx.x * 128;
  const int l15 = lane & 15, kg = lane >> 4;
  f32x4 acc[2][4] = {};
  for (int kk = 0; kk < 128; kk += 64) {
    #pragma unroll
    for (int it = 0; it < 4; ++it) {
      int c = t + it * 256;                 // 1024 chunks A
      int r = c >> 3, kc = (c & 7) * 8;
      uint4 v = make_uint4(0, 0, 0, 0);
      if (row0 + r < NN)
        v = *(const uint4*)(A + (size_t)(row0 + r) * 1024 + h * 128 + kk + kc);
      *(uint4*)&As[r][kc] = v;
    }
    #pragma unroll
    for (int it = 0; it < 2; ++it) {
      int c = t + it * 256;                 // 512 chunks B
      int r = c >> 3, kc = (c & 7) * 8;
      *(uint4*)&Bs[r][kc] = *(const uint4*)(w1t + (size_t)(h * 64 + r) * 128 + kk + kc);
    }
    __syncthreads();
    #pragma unroll
    for (int ks = 0; ks < 2; ++ks) {
      bf16x8 af[2], bfr[4];
      #pragma unroll
      for (int fi = 0; fi < 2; ++fi)
        af[fi] = *(const bf16x8*)&As[wid * 32 + fi * 16 + l15][ks * 32 + kg * 8];
      #pragma unroll
      for (int fj = 0; fj < 4; ++fj)
        bfr[fj] = *(const bf16x8*)&Bs[fj * 16 + l15][ks * 32 + kg * 8];
      #pragma unroll
      for (int fi = 0; fi < 2; ++fi)
        #pragma unroll
        for (int fj = 0; fj < 4; ++fj)
          acc[fi][fj] = __builtin_amdgcn_mfma_f32_16x16x32_bf16(af[fi], bfr[fj], acc[fi][fj], 0, 0, 0);
    }
    __syncthreads();
  }
  float bj[4];
  #pragma unroll
  for (int fj = 0; fj < 4; ++fj) bj[fj] = bias[h * 64 + fj * 16 + l15];
  #pragma unroll
  for (int fi = 0; fi < 2; ++fi) {
    const int rbase = row0 + wid * 32 + fi * 16 + kg * 4;
    #pragma unroll
    for (int r = 0; r < 4; ++r) {
      int row = rbase + r;
      if (row < NN) {
        #pragma unroll
        for (int fj = 0; fj < 4; ++fj)
          out[(size_t)row * 512 + h * 64 + fj * 16 + l15] = f2bf(elu(acc[fi][fj][r] + bj[fj]));
      }
    }
  }
}

// ====== GEMM2 (MFMA): feat2(f32) = out1e @ W2T^T, fused el2/er2 ==============
__global__ __launch_bounds__(256)
void gemm2_mfma(const unsigned short* __restrict__ A,     // out1e [NN][512] bf16
                const unsigned short* __restrict__ w2t,   // [64][512] bf16
                const float* __restrict__ al, const float* __restrict__ ar,
                float* __restrict__ C,                    // feat2 [NN][64] f32
                float* __restrict__ el, float* __restrict__ er) {
  __shared__ unsigned short As[128][72];
  __shared__ unsigned short Bs[64][72];
  const int t = threadIdx.x, lane = t & 63, wid = t >> 6;
  const int row0 = blockIdx.x * 128;
  const int l15 = lane & 15, kg = lane >> 4;
  f32x4 acc[2][4] = {};
  for (int kk = 0; kk < 512; kk += 64) {
    #pragma unroll
    for (int it = 0; it < 4; ++it) {
      int c = t + it * 256;
      int r = c >> 3, kc = (c & 7) * 8;
      uint4 v = make_uint4(0, 0, 0, 0);
      if (row0 + r < NN) v = *(const uint4*)(A + (size_t)(row0 + r) * 512 + kk + kc);
      *(uint4*)&As[r][kc] = v;
    }
    #pragma unroll
    for (int it = 0; it < 2; ++it) {
      int c = t + it * 256;
      int r = c >> 3, kc = (c & 7) * 8;
      *(uint4*)&Bs[r][kc] = *(const uint4*)(w2t + (size_t)r * 512 + kk + kc);
    }
    __syncthreads();
    #pragma unroll
    for (int ks = 0; ks < 2; ++ks) {
      bf16x8 af[2], bfr[4];
      #pragma unroll
      for (int fi = 0; fi < 2; ++fi)
        af[fi] = *(const bf16x8*)&As[wid * 32 + fi * 16 + l15][ks * 32 + kg * 8];
      #pragma unroll
      for (int fj = 0; fj < 4; ++fj)
        bfr[fj] = *(const bf16x8*)&Bs[fj * 16 + l15][ks * 32 + kg * 8];
      #pragma unroll
      for (int fi = 0; fi < 2; ++fi)
        #pragma unroll
        for (int fj = 0; fj < 4; ++fj)
          acc[fi][fj] = __builtin_amdgcn_mfma_f32_16x16x32_bf16(af[fi], bfr[fj], acc[fi][fj], 0, 0, 0);
    }
    __syncthreads();
  }
  float alf[4], arf[4];
  #pragma unroll
  for (int fj = 0; fj < 4; ++fj) { alf[fj] = al[fj * 16 + l15]; arf[fj] = ar[fj * 16 + l15]; }
  #pragma unroll
  for (int fi = 0; fi < 2; ++fi) {
    float pl[4] = {}, pr[4] = {};
    #pragma unroll
    for (int fj = 0; fj < 4; ++fj)
      #pragma unroll
      for (int r = 0; r < 4; ++r) {
        pl[r] = fmaf(acc[fi][fj][r], alf[fj], pl[r]);
        pr[r] = fmaf(acc[fi][fj][r], arf[fj], pr[r]);
      }
    const int rbase = row0 + wid * 32 + fi * 16 + kg * 4;
    #pragma unroll
    for (int r = 0; r < 4; ++r) {
      int row = rbase + r;
      if (row < NN) {
        #pragma unroll
        for (int fj = 0; fj < 4; ++fj) C[(size_t)row * 64 + fj * 16 + l15] = acc[fi][fj][r];
      }
    }
    #pragma unroll
    for (int s = 1; s <= 8; s <<= 1)
      #pragma unroll
      for (int r = 0; r < 4; ++r) {
        pl[r] += __shfl_xor(pl[r], s);
        pr[r] += __shfl_xor(pr[r], s);
      }
    if (l15 == 0) {
      #pragma unroll
      for (int r = 0; r < 4; ++r) {
        int row = rbase + r;
        if (row < NN) { el[row] = pl[r]; er[row] = pr[r]; }
      }
    }
  }
}

// ==== agg2f: single head, 4 nodes per wave, no-max softmax ===================
__global__ __launch_bounds__(256)
void agg2f_kernel(const float* __restrict__ feat,
                  const float* __restrict__ el, const float* __restrict__ er,
                  const int* __restrict__ srcs, const int* __restrict__ rowptr,
                  const float* __restrict__ bias, float* __restrict__ out, int N) {
  __shared__ float wlds[4][4][64];
  __shared__ int slds[4][4][64];
  int wv = threadIdx.x >> 6;
  int lane = threadIdx.x & 63;
  int nb = blockIdx.x * 16 + wv * 4;
  int n0 = nb, n1 = nb + 1, n2 = nb + 2, n3 = nb + 3;
  int p00 = 0, d0 = 0, p01 = 0, d1 = 0, p02 = 0, d2 = 0, p03 = 0, d3 = 0;
  if (n0 < N) { p00 = rowptr[n0]; d0 = rowptr[n0 + 1] - p00; }
  if (n1 < N) { p01 = rowptr[n1]; d1 = rowptr[n1 + 1] - p01; }
  if (n2 < N) { p02 = rowptr[n2]; d2 = rowptr[n2 + 1] - p02; }
  if (n3 < N) { p03 = rowptr[n3]; d3 = rowptr[n3 + 1] - p03; }
  float* wl0 = wlds[wv][0]; float* wl1 = wlds[wv][1];
  float* wl2 = wlds[wv][2]; float* wl3 = wlds[wv][3];
  int* sd0 = slds[wv][0]; int* sd1 = slds[wv][1];
  int* sd2 = slds[wv][2]; int* sd3 = slds[wv][3];

  if (d0 > 64 || d1 > 64 || d2 > 64 || d3 > 64) {
    // rare fallback: whole-wave per node, with max
    for (int q = 0; q < 4; ++q) {
      int n = q == 0 ? n0 : q == 1 ? n1 : q == 2 ? n2 : n3;
      if (n >= N) continue;
      int p0 = q == 0 ? p00 : q == 1 ? p01 : q == 2 ? p02 : p03;
      int deg = q == 0 ? d0 : q == 1 ? d1 : q == 2 ? d2 : d3;
      float acc = 0.f;
      if (deg > 0) {
        int p1 = p0 + deg;
        float ern = er[n];
        float m = -3.4e38f;
        for (int i = p0 + lane; i < p1; i += 64)
          m = fmaxf(m, lrelu(el[srcs[i]] + ern));
        #pragma unroll
        for (int st = 1; st <= 32; st <<= 1) m = fmaxf(m, __shfl_xor(m, st));
        float z = 0.f;
        for (int i = p0 + lane; i < p1; i += 64)
          z += __expf(lrelu(el[srcs[i]] + ern) - m);
        #pragma unroll
        for (int st = 1; st <= 32; st <<= 1) z += __shfl_xor(z, st);
        float iz = 1.f / z;
        for (int i = p0; i < p1; ++i) {
          int s0 = srcs[i];
          float w = __expf(lrelu(el[s0] + ern) - m) * iz;
          acc = fmaf(feat[(size_t)s0 * 64 + lane], w, acc);
        }
      }
      out[(size_t)n * 64 + lane] = acc + bias[lane];
    }
    return;
  }
  // fast path: stage unnormalized weights per node; iz kept in registers
  auto stage = [&](int n, int p0, int d, float* wl, int* sd) -> float {
    if (n >= N || d <= 0) return 0.f;
    float ern = er[n];
    float w = 0.f;
    if (lane < d) {
      int s = srcs[p0 + lane];
      sd[lane] = s;
      w = __expf(lrelu(el[s] + ern));
    }
    wl[lane] = w;
    float z = w;
    #pragma unroll
    for (int st = 1; st <= 32; st <<= 1) z += __shfl_xor(z, st);
    return 1.f / z;
  };
  float iz0 = stage(n0, p00, d0, wl0, sd0);
  float iz1 = stage(n1, p01, d1, wl1, sd1);
  float iz2 = stage(n2, p02, d2, wl2, sd2);
  float iz3 = stage(n3, p03, d3, wl3, sd3);
  asm volatile("s_waitcnt lgkmcnt(0)" ::: "memory");
  float a0 = 0.f, a1 = 0.f, a2 = 0.f, a3 = 0.f;
  int dmax = max(max(d0, d1), max(d2, d3));
  for (int i = 0; i < dmax; ++i) {
    if (i < d0) a0 = fmaf(feat[(size_t)sd0[i] * 64 + lane], wl0[i], a0);
    if (i < d1) a1 = fmaf(feat[(size_t)sd1[i] * 64 + lane], wl1[i], a1);
    if (i < d2) a2 = fmaf(feat[(size_t)sd2[i] * 64 + lane], wl2[i], a2);
    if (i < d3) a3 = fmaf(feat[(size_t)sd3[i] * 64 + lane], wl3[i], a3);
  }
  float bv = bias[lane];
  if (n0 < N) out[(size_t)n0 * 64 + lane] = a0 * iz0 + bv;
  if (n1 < N) out[(size_t)n1 * 64 + lane] = a1 * iz1 + bv;
  if (n2 < N) out[(size_t)n2 * 64 + lane] = a2 * iz2 + bv;
  if (n3 < N) out[(size_t)n3 * 64 + lane] = a3 * iz3 + bv;
}

extern "C" void kernel_launch(void* const* d_in, const int* in_sizes, int n_in,
                              void* d_out, int out_size, void* d_ws, size_t ws_size,
                              hipStream_t stream) {
  const float* x   = (const float*)d_in[0];
  const int*   src = (const int*)d_in[1];
  const int*   dst = (const int*)d_in[2];
  const float* W1  = (const float*)d_in[3];
  const float* al1 = (const float*)d_in[4];
  const float* ar1 = (const float*)d_in[5];
  const float* b1  = (const float*)d_in[6];
  const float* W2  = (const float*)d_in[7];
  const float* al2 = (const float*)d_in[8];
  const float* ar2 = (const float*)d_in[9];
  const float* b2  = (const float*)d_in[10];
  float* out = (float*)d_out;

  char* p = (char*)d_ws;
  auto alloc = [&](size_t bytes) { void* r = (void*)p; p += (bytes + 255) & ~(size_t)255; return r; };
  unsigned short* xb    = (unsigned short*)alloc((size_t)NN * 128 * 2);   // 12.8 MB
  unsigned short* w1t   = (unsigned short*)alloc((size_t)512 * 128 * 2);
  unsigned short* w2t   = (unsigned short*)alloc((size_t)64 * 512 * 2);
  unsigned short* walb  = (unsigned short*)alloc((size_t)16 * 128 * 2);
  unsigned short* xagg  = (unsigned short*)alloc((size_t)NN * 1024 * 2);  // 102.4 MB
  unsigned short* out1e = (unsigned short*)alloc((size_t)NN * 512 * 2);   // 51.2 MB
  float* el1   = (float*)alloc((size_t)NN * 8 * 4);
  float* er1   = (float*)alloc((size_t)NN * 8 * 4);
  float* feat2 = (float*)alloc((size_t)NN * 64 * 4);
  float* el2   = (float*)alloc((size_t)NN * 4);
  float* er2   = (float*)alloc((size_t)NN * 4);
  int* rowptr  = (int*)alloc((size_t)(NN + 1) * 4);
  int* srcs    = (int*)alloc((size_t)NE * 4);
  int* cnt     = (int*)alloc((size_t)NN * 4);
  int* fill    = (int*)alloc((size_t)NN * 4);

  hipMemsetAsync(cnt, 0, (size_t)NN * 4, stream);
  hipMemsetAsync(fill, 0, (size_t)NN * 4, stream);

  // prep (cvt_x + W transposes + walb + hist)
  prep_all_kernel<<<(1700352 + 255) / 256, 256, 0, stream>>>(
      x, xb, W1, W2, al1, ar1, w1t, w2t, walb, dst, cnt);

  // CSR
  scan_kernel<<<1, 1024, 0, stream>>>(cnt, rowptr, NN);
  scatter_kernel<<<(NE + 255) / 256, 256, 0, stream>>>(dst, src, rowptr, fill, srcs, NE);

  // layer 1 (linearity-reordered)
  eler_kernel<<<(NN + 63) / 64, 256, 0, stream>>>(xb, walb, el1, er1);
  aggx_kernel<<<(NN + 15) / 16, 256, 0, stream>>>(xb, el1, er1, srcs, rowptr, xagg, NN);
  gemm1b_mfma<<<dim3((NN + 127) / 128, 8), 256, 0, stream>>>(xagg, w1t, b1, out1e);

  // layer 2
  gemm2_mfma<<<(NN + 127) / 128, 256, 0, stream>>>(out1e, w2t, al2, ar2, feat2, el2, er2);
  agg2f_kernel<<<(NN + 15) / 16, 256, 0, stream>>>(feat2, el2, er2, srcs, rowptr, b2, out, NN);
}

// Round 16
// 373.235 us; speedup vs baseline: 1.1230x; 1.1230x over previous
//
#include <hip/hip_runtime.h>
#include <cstdint>

// GAT 2-layer: N=50000, E=800000.
// Layer 1 via linearity: aggregate x (256B bf16 rows), then batched per-head
// MFMA GEMM. aggx: 2 nodes/wave (LDS-balanced optimum). agg2f: 4 nodes/wave
// (not LDS-capped). No-max softmax (exp(e) direct, 1/z at end).
#define NN 50000
#define NE 800000

typedef short bf16x8 __attribute__((ext_vector_type(8)));
typedef float f32x4 __attribute__((ext_vector_type(4)));
typedef float f32x2 __attribute__((ext_vector_type(2)));

__device__ __forceinline__ float lrelu(float x) { return x > 0.f ? x : 0.2f * x; }
__device__ __forceinline__ float elu(float x) { return x > 0.f ? x : __expf(x) - 1.f; }
__device__ __forceinline__ unsigned short f2bf(float f) {
  unsigned u = __float_as_uint(f);
  unsigned r = (u + 0x7FFFu + ((u >> 16) & 1u)) >> 16;   // RNE
  return (unsigned short)r;
}
__device__ __forceinline__ f32x2 fma2(f32x2 a, f32x2 b, f32x2 c) {
#if __has_builtin(__builtin_elementwise_fma)
  return __builtin_elementwise_fma(a, b, c);
#else
  f32x2 r; r[0] = fmaf(a[0], b[0], c[0]); r[1] = fmaf(a[1], b[1], c[1]); return r;
#endif
}

// ===================== prep (fused cvt_x + w-transposes + walb + hist) ======
__global__ __launch_bounds__(256)
void prep_all_kernel(const float* __restrict__ x, unsigned short* __restrict__ xb,
                     const float* __restrict__ W1, const float* __restrict__ W2,
                     const float* __restrict__ al, const float* __restrict__ ar,
                     unsigned short* __restrict__ w1t, unsigned short* __restrict__ w2t,
                     unsigned short* __restrict__ walb,
                     const int* __restrict__ dst, int* __restrict__ cnt) {
  int idx = blockIdx.x * 256 + threadIdx.x;
  if (idx < 800000) {                          // cvt_x: 8 elems each
    float4 a = *(const float4*)(x + (size_t)idx * 8);
    float4 b = *(const float4*)(x + (size_t)idx * 8 + 4);
    unsigned short us[8] = { f2bf(a.x), f2bf(a.y), f2bf(a.z), f2bf(a.w),
                             f2bf(b.x), f2bf(b.y), f2bf(b.z), f2bf(b.w) };
    *(uint4*)(xb + (size_t)idx * 8) = *(const uint4*)us;
  } else if (idx < 865536) {                   // W1 -> w1t [512][128]
    int t = idx - 800000;
    int k = t >> 9, c = t & 511;
    w1t[(size_t)c * 128 + k] = f2bf(W1[t]);
  } else if (idx < 898304) {                   // W2 -> w2t [64][512]
    int t = idx - 865536;
    int k = t >> 6, c = t & 63;
    w2t[(size_t)c * 512 + k] = f2bf(W2[t]);
  } else if (idx < 900352) {                   // walb [16][128]
    int t = idx - 898304;
    int k = t >> 4, o = t & 15, h = o & 7;
    const float* a = (o < 8) ? al : ar;
    float s = 0.f;
    #pragma unroll 8
    for (int d = 0; d < 64; ++d)
      s += W1[(size_t)k * 512 + h * 64 + d] * a[h * 64 + d];
    walb[o * 128 + k] = f2bf(s);
  } else if (idx < 1700352) {                  // hist
    int e = idx - 900352;
    atomicAdd(&cnt[dst[e]], 1);
  }
}

// ===== eler: el1/er1 [N,8] = xb @ walb^T via MFMA, 16 nodes/wave ============
__global__ __launch_bounds__(256)
void eler_kernel(const unsigned short* __restrict__ xb,    // [NN][128]
                 const unsigned short* __restrict__ walb,  // [16][128]
                 float* __restrict__ el, float* __restrict__ er) {
  int wv = threadIdx.x >> 6, lane = threadIdx.x & 63;
  int row0 = blockIdx.x * 64 + wv * 16;
  const int l15 = lane & 15, kg = lane >> 4;
  f32x4 c = {0.f, 0.f, 0.f, 0.f};
  #pragma unroll
  for (int ks = 0; ks < 4; ++ks) {
    bf16x8 a = {};
    int row = row0 + l15;
    if (row < NN) a = *(const bf16x8*)(xb + (size_t)row * 128 + ks * 32 + kg * 8);
    bf16x8 b = *(const bf16x8*)(walb + (size_t)l15 * 128 + ks * 32 + kg * 8);
    c = __builtin_amdgcn_mfma_f32_16x16x32_bf16(a, b, c, 0, 0, 0);
  }
  #pragma unroll
  for (int r = 0; r < 4; ++r) {
    int row = row0 + kg * 4 + r;
    if (row < NN) {
      if (l15 < 8) el[(size_t)row * 8 + l15] = c[r];
      else         er[(size_t)row * 8 + (l15 - 8)] = c[r];
    }
  }
}

// ===================== CSR scan + scatter ====================================
__global__ __launch_bounds__(1024)
void scan_kernel(const int* __restrict__ cnt, int* __restrict__ rowptr, int N) {
  __shared__ int sums[1024];
  int t = threadIdx.x;
  const int CH = (N + 1023) / 1024;
  int s0 = t * CH, s1 = s0 + CH; if (s1 > N) s1 = N;
  int s = 0;
  for (int i = s0; i < s1; ++i) s += cnt[i];
  sums[t] = s;
  __syncthreads();
  for (int d = 1; d < 1024; d <<= 1) {
    int v = sums[t];
    int u = (t >= d) ? sums[t - d] : 0;
    __syncthreads();
    sums[t] = v + u;
    __syncthreads();
  }
  int run = (t == 0) ? 0 : sums[t - 1];
  for (int i = s0; i < s1; ++i) { rowptr[i] = run; run += cnt[i]; }
  if (t == 1023) rowptr[N] = sums[1023];
}

__global__ void scatter_kernel(const int* __restrict__ dst, const int* __restrict__ src,
                               const int* __restrict__ rowptr, int* __restrict__ fill,
                               int* __restrict__ srcs, int E) {
  int e = blockIdx.x * 256 + threadIdx.x;
  if (e >= E) return;
  int d = dst[e];
  int pos = atomicAdd(&fill[d], 1);
  srcs[rowptr[d] + pos] = src[e];
}

// ==== aggx: xagg[n,h,:] = sum_e alpha_e,h * xb[src_e,:]; 2 nodes per wave ====
__global__ __launch_bounds__(256)
void aggx_kernel(const unsigned short* __restrict__ xb,
                 const float* __restrict__ el, const float* __restrict__ er,
                 const int* __restrict__ srcs, const int* __restrict__ rowptr,
                 unsigned short* __restrict__ xagg, int N) {
  __shared__ float wlds[4][2][64 * 8];
  __shared__ int slds[4][2][64];
  __shared__ float mzlds[4][2][8];
  int wv = threadIdx.x >> 6;
  int lane = threadIdx.x & 63;
  const int myh = lane >> 3, j = lane & 7;
  int n0 = blockIdx.x * 8 + wv * 2, n1 = n0 + 1;
  bool v0 = n0 < N, v1 = n1 < N;
  int p00 = 0, d0 = 0, p01 = 0, d1 = 0;
  if (v0) { p00 = rowptr[n0]; d0 = rowptr[n0 + 1] - p00; }
  if (v1) { p01 = rowptr[n1]; d1 = rowptr[n1 + 1] - p01; }
  float* wl0 = wlds[wv][0]; float* wl1 = wlds[wv][1];
  int* sd0 = slds[wv][0];   int* sd1 = slds[wv][1];
  float* mz0 = mzlds[wv][0]; float* mz1 = mzlds[wv][1];

  if (d0 > 64 || d1 > 64) {
    // ---- rare fallback: whole-wave per node, 3-pass chunked with max ----
    for (int q = 0; q < 2; ++q) {
      int n = q ? n1 : n0;
      if (n >= N) continue;
      int p0 = q ? p01 : p00;
      int deg = q ? d1 : d0;
      f32x2 a00 = {0.f, 0.f}, a01 = a00, a10 = a00, a11 = a00;
      f32x2 a20 = a00, a21 = a00, a30 = a00, a31 = a00;
      if (deg > 0) {
        int p1 = p0 + deg;
        float er8[8];
        *(float4*)&er8[0] = *(const float4*)(er + (size_t)n * 8);
        *(float4*)&er8[4] = *(const float4*)(er + (size_t)n * 8 + 4);
        float erh = er8[0];
        #pragma unroll
        for (int h = 1; h < 8; ++h) erh = (myh == h) ? er8[h] : erh;
        float m = -3.4e38f;
        for (int i = p0 + j; i < p1; i += 8)
          m = fmaxf(m, lrelu(el[(size_t)srcs[i] * 8 + myh] + erh));
        m = fmaxf(m, __shfl_xor(m, 1));
        m = fmaxf(m, __shfl_xor(m, 2));
        m = fmaxf(m, __shfl_xor(m, 4));
        float z = 0.f;
        for (int i = p0 + j; i < p1; i += 8)
          z += __expf(lrelu(el[(size_t)srcs[i] * 8 + myh] + erh) - m);
        z += __shfl_xor(z, 1); z += __shfl_xor(z, 2); z += __shfl_xor(z, 4);
        if (j == 0) { mz0[myh] = m; mz1[myh] = 1.f / z; }
        asm volatile("s_waitcnt lgkmcnt(0)" ::: "memory");
        float m8[8];
        #pragma unroll
        for (int h = 0; h < 8; ++h) m8[h] = mz0[h];
        for (int c0 = p0; c0 < p1; c0 += 64) {
          int cnt = min(64, p1 - c0);
          if (lane < cnt) {
            int s = srcs[c0 + lane];
            sd0[lane] = s;
            float elr[8];
            *(float4*)&elr[0] = *(const float4*)(el + (size_t)s * 8);
            *(float4*)&elr[4] = *(const float4*)(el + (size_t)s * 8 + 4);
            #pragma unroll
            for (int h = 0; h < 8; ++h)
              wl0[lane * 8 + h] = __expf(lrelu(elr[h] + er8[h]) - m8[h]);
          }
          asm volatile("s_waitcnt lgkmcnt(0)" ::: "memory");
          for (int i = 0; i < cnt; ++i) {
            int s2 = sd0[i];
            unsigned u = *(const unsigned*)(xb + (size_t)s2 * 128 + lane * 2);
            float4 wa = *(const float4*)&wl0[i * 8];
            float4 wb = *(const float4*)&wl0[i * 8 + 4];
            f32x2 lod, hid;
            lod[0] = lod[1] = __uint_as_float(u << 16);
            hid[0] = hid[1] = __uint_as_float(u & 0xFFFF0000u);
            f32x2 w01, w23, w45, w67;
            w01[0] = wa.x; w01[1] = wa.y; w23[0] = wa.z; w23[1] = wa.w;
            w45[0] = wb.x; w45[1] = wb.y; w67[0] = wb.z; w67[1] = wb.w;
            a00 = fma2(w01, lod, a00); a01 = fma2(w01, hid, a01);
            a10 = fma2(w23, lod, a10); a11 = fma2(w23, hid, a11);
            a20 = fma2(w45, lod, a20); a21 = fma2(w45, hid, a21);
            a30 = fma2(w67, lod, a30); a31 = fma2(w67, hid, a31);
          }
          asm volatile("s_waitcnt lgkmcnt(0)" ::: "memory");
        }
        float iz8[8];
        #pragma unroll
        for (int h = 0; h < 8; ++h) iz8[h] = mz1[h];
        f32x2 s01, s23, s45, s67;
        s01[0] = iz8[0]; s01[1] = iz8[1]; s23[0] = iz8[2]; s23[1] = iz8[3];
        s45[0] = iz8[4]; s45[1] = iz8[5]; s67[0] = iz8[6]; s67[1] = iz8[7];
        a00 *= s01; a01 *= s01; a10 *= s23; a11 *= s23;
        a20 *= s45; a21 *= s45; a30 *= s67; a31 *= s67;
      }
      unsigned short* op = xagg + (size_t)n * 1024;
      unsigned pk;
      pk = (unsigned)f2bf(a00[0]) | ((unsigned)f2bf(a01[0]) << 16);
      *(unsigned*)(op + 0 * 128 + lane * 2) = pk;
      pk = (unsigned)f2bf(a00[1]) | ((unsigned)f2bf(a01[1]) << 16);
      *(unsigned*)(op + 1 * 128 + lane * 2) = pk;
      pk = (unsigned)f2bf(a10[0]) | ((unsigned)f2bf(a11[0]) << 16);
      *(unsigned*)(op + 2 * 128 + lane * 2) = pk;
      pk = (unsigned)f2bf(a10[1]) | ((unsigned)f2bf(a11[1]) << 16);
      *(unsigned*)(op + 3 * 128 + lane * 2) = pk;
      pk = (unsigned)f2bf(a20[0]) | ((unsigned)f2bf(a21[0]) << 16);
      *(unsigned*)(op + 4 * 128 + lane * 2) = pk;
      pk = (unsigned)f2bf(a20[1]) | ((unsigned)f2bf(a21[1]) << 16);
      *(unsigned*)(op + 5 * 128 + lane * 2) = pk;
      pk = (unsigned)f2bf(a30[0]) | ((unsigned)f2bf(a31[0]) << 16);
      *(unsigned*)(op + 6 * 128 + lane * 2) = pk;
      pk = (unsigned)f2bf(a30[1]) | ((unsigned)f2bf(a31[1]) << 16);
      *(unsigned*)(op + 7 * 128 + lane * 2) = pk;
    }
    return;
  }

  // ---- fast path: no-max softmax, 2 nodes interleaved ----
  if (v0 && d0 > 0) {
    float er8[8];
    *(float4*)&er8[0] = *(const float4*)(er + (size_t)n0 * 8);
    *(float4*)&er8[4] = *(const float4*)(er + (size_t)n0 * 8 + 4);
    float w8[8] = {0.f, 0.f, 0.f, 0.f, 0.f, 0.f, 0.f, 0.f};
    if (lane < d0) {
      int s = srcs[p00 + lane];
      sd0[lane] = s;
      float elr[8];
      *(float4*)&elr[0] = *(const float4*)(el + (size_t)s * 8);
      *(float4*)&elr[4] = *(const float4*)(el + (size_t)s * 8 + 4);
      #pragma unroll
      for (int h = 0; h < 8; ++h) w8[h] = __expf(lrelu(elr[h] + er8[h]));
    }
    #pragma unroll
    for (int h = 0; h < 8; ++h) wl0[lane * 8 + h] = w8[h];
  }
  if (v1 && d1 > 0) {
    float er8[8];
    *(float4*)&er8[0] = *(const float4*)(er + (size_t)n1 * 8);
    *(float4*)&er8[4] = *(const float4*)(er + (size_t)n1 * 8 + 4);
    float w8[8] = {0.f, 0.f, 0.f, 0.f, 0.f, 0.f, 0.f, 0.f};
    if (lane < d1) {
      int s = srcs[p01 + lane];
      sd1[lane] = s;
      float elr[8];
      *(float4*)&elr[0] = *(const float4*)(el + (size_t)s * 8);
      *(float4*)&elr[4] = *(const float4*)(el + (size_t)s * 8 + 4);
      #pragma unroll
      for (int h = 0; h < 8; ++h) w8[h] = __expf(lrelu(elr[h] + er8[h]));
    }
    #pragma unroll
    for (int h = 0; h < 8; ++h) wl1[lane * 8 + h] = w8[h];
  }
  asm volatile("s_waitcnt lgkmcnt(0)" ::: "memory");
  // z-reduce per node: roles (myh, j): 8 strided reads + 3 shfl
  if (v0 && d0 > 0) {
    float z = 0.f;
    #pragma unroll
    for (int t2 = 0; t2 < 8; ++t2) z += wl0[(t2 * 8 + j) * 8 + myh];
    z += __shfl_xor(z, 1); z += __shfl_xor(z, 2); z += __shfl_xor(z, 4);
    if (j == 0) mz0[myh] = 1.f / z;
  }
  if (v1 && d1 > 0) {
    float z = 0.f;
    #pragma unroll
    for (int t2 = 0; t2 < 8; ++t2) z += wl1[(t2 * 8 + j) * 8 + myh];
    z += __shfl_xor(z, 1); z += __shfl_xor(z, 2); z += __shfl_xor(z, 4);
    if (j == 0) mz1[myh] = 1.f / z;
  }
  asm volatile("s_waitcnt lgkmcnt(0)" ::: "memory");
  // interleaved aggregation: two independent chains
  f32x2 aA00 = {0.f, 0.f}, aA01 = aA00, aA10 = aA00, aA11 = aA00;
  f32x2 aA20 = aA00, aA21 = aA00, aA30 = aA00, aA31 = aA00;
  f32x2 aB00 = aA00, aB01 = aA00, aB10 = aA00, aB11 = aA00;
  f32x2 aB20 = aA00, aB21 = aA00, aB30 = aA00, aB31 = aA00;
  auto stepA = [&](int i) {
    int s2 = sd0[i];
    unsigned u = *(const unsigned*)(xb + (size_t)s2 * 128 + lane * 2);
    float4 wa = *(const float4*)&wl0[i * 8];
    float4 wb = *(const float4*)&wl0[i * 8 + 4];
    f32x2 lod, hid;
    lod[0] = lod[1] = __uint_as_float(u << 16);
    hid[0] = hid[1] = __uint_as_float(u & 0xFFFF0000u);
    f32x2 w01, w23, w45, w67;
    w01[0] = wa.x; w01[1] = wa.y; w23[0] = wa.z; w23[1] = wa.w;
    w45[0] = wb.x; w45[1] = wb.y; w67[0] = wb.z; w67[1] = wb.w;
    aA00 = fma2(w01, lod, aA00); aA01 = fma2(w01, hid, aA01);
    aA10 = fma2(w23, lod, aA10); aA11 = fma2(w23, hid, aA11);
    aA20 = fma2(w45, lod, aA20); aA21 = fma2(w45, hid, aA21);
    aA30 = fma2(w67, lod, aA30); aA31 = fma2(w67, hid, aA31);
  };
  auto stepB = [&](int i) {
    int s2 = sd1[i];
    unsigned u = *(const unsigned*)(xb + (size_t)s2 * 128 + lane * 2);
    float4 wa = *(const float4*)&wl1[i * 8];
    float4 wb = *(const float4*)&wl1[i * 8 + 4];
    f32x2 lod, hid;
    lod[0] = lod[1] = __uint_as_float(u << 16);
    hid[0] = hid[1] = __uint_as_float(u & 0xFFFF0000u);
    f32x2 w01, w23, w45, w67;
    w01[0] = wa.x; w01[1] = wa.y; w23[0] = wa.z; w23[1] = wa.w;
    w45[0] = wb.x; w45[1] = wb.y; w67[0] = wb.z; w67[1] = wb.w;
    aB00 = fma2(w01, lod, aB00); aB01 = fma2(w01, hid, aB01);
    aB10 = fma2(w23, lod, aB10); aB11 = fma2(w23, hid, aB11);
    aB20 = fma2(w45, lod, aB20); aB21 = fma2(w45, hid, aB21);
    aB30 = fma2(w67, lod, aB30); aB31 = fma2(w67, hid, aB31);
  };
  int dmin = min(d0, d1);
  int i = 0;
  for (; i < dmin; ++i) { stepA(i); stepB(i); }
  for (int k = i; k < d0; ++k) stepA(k);
  for (int k = i; k < d1; ++k) stepB(k);
  // scale by 1/z and store
  if (v0) {
    if (d0 > 0) {
      float iz[8];
      #pragma unroll
      for (int h = 0; h < 8; ++h) iz[h] = mz0[h];
      f32x2 s01, s23, s45, s67;
      s01[0] = iz[0]; s01[1] = iz[1]; s23[0] = iz[2]; s23[1] = iz[3];
      s45[0] = iz[4]; s45[1] = iz[5]; s67[0] = iz[6]; s67[1] = iz[7];
      aA00 *= s01; aA01 *= s01; aA10 *= s23; aA11 *= s23;
      aA20 *= s45; aA21 *= s45; aA30 *= s67; aA31 *= s67;
    }
    unsigned short* op = xagg + (size_t)n0 * 1024;
    unsigned pk;
    pk = (unsigned)f2bf(aA00[0]) | ((unsigned)f2bf(aA01[0]) << 16);
    *(unsigned*)(op + 0 * 128 + lane * 2) = pk;
    pk = (unsigned)f2bf(aA00[1]) | ((unsigned)f2bf(aA01[1]) << 16);
    *(unsigned*)(op + 1 * 128 + lane * 2) = pk;
    pk = (unsigned)f2bf(aA10[0]) | ((unsigned)f2bf(aA11[0]) << 16);
    *(unsigned*)(op + 2 * 128 + lane * 2) = pk;
    pk = (unsigned)f2bf(aA10[1]) | ((unsigned)f2bf(aA11[1]) << 16);
    *(unsigned*)(op + 3 * 128 + lane * 2) = pk;
    pk = (unsigned)f2bf(aA20[0]) | ((unsigned)f2bf(aA21[0]) << 16);
    *(unsigned*)(op + 4 * 128 + lane * 2) = pk;
    pk = (unsigned)f2bf(aA20[1]) | ((unsigned)f2bf(aA21[1]) << 16);
    *(unsigned*)(op + 5 * 128 + lane * 2) = pk;
    pk = (unsigned)f2bf(aA30[0]) | ((unsigned)f2bf(aA31[0]) << 16);
    *(unsigned*)(op + 6 * 128 + lane * 2) = pk;
    pk = (unsigned)f2bf(aA30[1]) | ((unsigned)f2bf(aA31[1]) << 16);
    *(unsigned*)(op + 7 * 128 + lane * 2) = pk;
  }
  if (v1) {
    if (d1 > 0) {
      float iz[8];
      #pragma unroll
      for (int h = 0; h < 8; ++h) iz[h] = mz1[h];
      f32x2 s01, s23, s45, s67;
      s01[0] = iz[0]; s01[1] = iz[1]; s23[0] = iz[2]; s23[1] = iz[3];
      s45[0] = iz[4]; s45[1] = iz[5]; s67[0] = iz[6]; s67[1] = iz[7];
      aB00 *= s01; aB01 *= s01; aB10 *= s23; aB11 *= s23;
      aB20 *= s45; aB21 *= s45; aB30 *= s67; aB31 *= s67;
    }
    unsigned short* op = xagg + (size_t)n1 * 1024;
    unsigned pk;
    pk = (unsigned)f2bf(aB00[0]) | ((unsigned)f2bf(aB01[0]) << 16);
    *(unsigned*)(op + 0 * 128 + lane * 2) = pk;
    pk = (unsigned)f2bf(aB00[1]) | ((unsigned)f2bf(aB01[1]) << 16);
    *(unsigned*)(op + 1 * 128 + lane * 2) = pk;
    pk = (unsigned)f2bf(aB10[0]) | ((unsigned)f2bf(aB11[0]) << 16);
    *(unsigned*)(op + 2 * 128 + lane * 2) = pk;
    pk = (unsigned)f2bf(aB10[1]) | ((unsigned)f2bf(aB11[1]) << 16);
    *(unsigned*)(op + 3 * 128 + lane * 2) = pk;
    pk = (unsigned)f2bf(aB20[0]) | ((unsigned)f2bf(aB21[0]) << 16);
    *(unsigned*)(op + 4 * 128 + lane * 2) = pk;
    pk = (unsigned)f2bf(aB20[1]) | ((unsigned)f2bf(aB21[1]) << 16);
    *(unsigned*)(op + 5 * 128 + lane * 2) = pk;
    pk = (unsigned)f2bf(aB30[0]) | ((unsigned)f2bf(aB31[0]) << 16);
    *(unsigned*)(op + 6 * 128 + lane * 2) = pk;
    pk = (unsigned)f2bf(aB30[1]) | ((unsigned)f2bf(aB31[1]) << 16);
    *(unsigned*)(op + 7 * 128 + lane * 2) = pk;
  }
}

// ===== gemm1b: out1e[:, h*64:+64] = elu(xagg[:,h,:] @ W1_h + b1_h), bf16 =====
__global__ __launch_bounds__(256)
void gemm1b_mfma(const unsigned short* __restrict__ A,     // xagg [NN][8][128]
                 const unsigned short* __restrict__ w1t,   // [512][128]
                 const float* __restrict__ bias,           // b1 [512]
                 unsigned short* __restrict__ out) {       // out1e [NN][512]
  __shared__ unsigned short As[128][72];
  __shared__ unsigned short Bs[64][72];
  const int t = threadIdx.x, lane = t & 63, wid = t >> 6;
  const int h = blockIdx.y;
  const int row0 = blockIdx.x * 128;
  const int l15 = lane & 15, kg = lane >> 4;
  f32x4 acc[2][4] = {};
  for (int kk = 0; kk < 128; kk += 64) {
    #pragma unroll
    for (int it = 0; it < 4; ++it) {
      int c = t + it * 256;                 // 1024 chunks A
      int r = c >> 3, kc = (c & 7) * 8;
      uint4 v = make_uint4(0, 0, 0, 0);
      if (row0 + r < NN)
        v = *(const uint4*)(A + (size_t)(row0 + r) * 1024 + h * 128 + kk + kc);
      *(uint4*)&As[r][kc] = v;
    }
    #pragma unroll
    for (int it = 0; it < 2; ++it) {
      int c = t + it * 256;                 // 512 chunks B
      int r = c >> 3, kc = (c & 7) * 8;
      *(uint4*)&Bs[r][kc] = *(const uint4*)(w1t + (size_t)(h * 64 + r) * 128 + kk + kc);
    }
    __syncthreads();
    #pragma unroll
    for (int ks = 0; ks < 2; ++ks) {
      bf16x8 af[2], bfr[4];
      #pragma unroll
      for (int fi = 0; fi < 2; ++fi)
        af[fi] = *(const bf16x8*)&As[wid * 32 + fi * 16 + l15][ks * 32 + kg * 8];
      #pragma unroll
      for (int fj = 0; fj < 4; ++fj)
        bfr[fj] = *(const bf16x8*)&Bs[fj * 16 + l15][ks * 32 + kg * 8];
      #pragma unroll
      for (int fi = 0; fi < 2; ++fi)
        #pragma unroll
        for (int fj = 0; fj < 4; ++fj)
          acc[fi][fj] = __builtin_amdgcn_mfma_f32_16x16x32_bf16(af[fi], bfr[fj], acc[fi][fj], 0, 0, 0);
    }
    __syncthreads();
  }
  float bj[4];
  #pragma unroll
  for (int fj = 0; fj < 4; ++fj) bj[fj] = bias[h * 64 + fj * 16 + l15];
  #pragma unroll
  for (int fi = 0; fi < 2; ++fi) {
    const int rbase = row0 + wid * 32 + fi * 16 + kg * 4;
    #pragma unroll
    for (int r = 0; r < 4; ++r) {
      int row = rbase + r;
      if (row < NN) {
        #pragma unroll
        for (int fj = 0; fj < 4; ++fj)
          out[(size_t)row * 512 + h * 64 + fj * 16 + l15] = f2bf(elu(acc[fi][fj][r] + bj[fj]));
      }
    }
  }
}

// ====== GEMM2 (MFMA): feat2(f32) = out1e @ W2T^T, fused el2/er2 ==============
__global__ __launch_bounds__(256)
void gemm2_mfma(const unsigned short* __restrict__ A,     // out1e [NN][512] bf16
                const unsigned short* __restrict__ w2t,   // [64][512] bf16
                const float* __restrict__ al, const float* __restrict__ ar,
                float* __restrict__ C,                    // feat2 [NN][64] f32
                float* __restrict__ el, float* __restrict__ er) {
  __shared__ unsigned short As[128][72];
  __shared__ unsigned short Bs[64][72];
  const int t = threadIdx.x, lane = t & 63, wid = t >> 6;
  const int row0 = blockIdx.x * 128;
  const int l15 = lane & 15, kg = lane >> 4;
  f32x4 acc[2][4] = {};
  for (int kk = 0; kk < 512; kk += 64) {
    #pragma unroll
    for (int it = 0; it < 4; ++it) {
      int c = t + it * 256;
      int r = c >> 3, kc = (c & 7) * 8;
      uint4 v = make_uint4(0, 0, 0, 0);
      if (row0 + r < NN) v = *(const uint4*)(A + (size_t)(row0 + r) * 512 + kk + kc);
      *(uint4*)&As[r][kc] = v;
    }
    #pragma unroll
    for (int it = 0; it < 2; ++it) {
      int c = t + it * 256;
      int r = c >> 3, kc = (c & 7) * 8;
      *(uint4*)&Bs[r][kc] = *(const uint4*)(w2t + (size_t)r * 512 + kk + kc);
    }
    __syncthreads();
    #pragma unroll
    for (int ks = 0; ks < 2; ++ks) {
      bf16x8 af[2], bfr[4];
      #pragma unroll
      for (int fi = 0; fi < 2; ++fi)
        af[fi] = *(const bf16x8*)&As[wid * 32 + fi * 16 + l15][ks * 32 + kg * 8];
      #pragma unroll
      for (int fj = 0; fj < 4; ++fj)
        bfr[fj] = *(const bf16x8*)&Bs[fj * 16 + l15][ks * 32 + kg * 8];
      #pragma unroll
      for (int fi = 0; fi < 2; ++fi)
        #pragma unroll
        for (int fj = 0; fj < 4; ++fj)
          acc[fi][fj] = __builtin_amdgcn_mfma_f32_16x16x32_bf16(af[fi], bfr[fj], acc[fi][fj], 0, 0, 0);
    }
    __syncthreads();
  }
  float alf[4], arf[4];
  #pragma unroll
  for (int fj = 0; fj < 4; ++fj) { alf[fj] = al[fj * 16 + l15]; arf[fj] = ar[fj * 16 + l15]; }
  #pragma unroll
  for (int fi = 0; fi < 2; ++fi) {
    float pl[4] = {}, pr[4] = {};
    #pragma unroll
    for (int fj = 0; fj < 4; ++fj)
      #pragma unroll
      for (int r = 0; r < 4; ++r) {
        pl[r] = fmaf(acc[fi][fj][r], alf[fj], pl[r]);
        pr[r] = fmaf(acc[fi][fj][r], arf[fj], pr[r]);
      }
    const int rbase = row0 + wid * 32 + fi * 16 + kg * 4;
    #pragma unroll
    for (int r = 0; r < 4; ++r) {
      int row = rbase + r;
      if (row < NN) {
        #pragma unroll
        for (int fj = 0; fj < 4; ++fj) C[(size_t)row * 64 + fj * 16 + l15] = acc[fi][fj][r];
      }
    }
    #pragma unroll
    for (int s = 1; s <= 8; s <<= 1)
      #pragma unroll
      for (int r = 0; r < 4; ++r) {
        pl[r] += __shfl_xor(pl[r], s);
        pr[r] += __shfl_xor(pr[r], s);
      }
    if (l15 == 0) {
      #pragma unroll
      for (int r = 0; r < 4; ++r) {
        int row = rbase + r;
        if (row < NN) { el[row] = pl[r]; er[row] = pr[r]; }
      }
    }
  }
}

// ==== agg2f: single head, 4 nodes per wave, no-max softmax ===================
__global__ __launch_bounds__(256)
void agg2f_kernel(const float* __restrict__ feat,
                  const float* __restrict__ el, const float* __restrict__ er,
                  const int* __restrict__ srcs, const int* __restrict__ rowptr,
                  const float* __restrict__ bias, float* __restrict__ out, int N) {
  __shared__ float wlds[4][4][64];
  __shared__ int slds[4][4][64];
  int wv = threadIdx.x >> 6;
  int lane = threadIdx.x & 63;
  int nb = blockIdx.x * 16 + wv * 4;
  int n0 = nb, n1 = nb + 1, n2 = nb + 2, n3 = nb + 3;
  int p00 = 0, d0 = 0, p01 = 0, d1 = 0, p02 = 0, d2 = 0, p03 = 0, d3 = 0;
  if (n0 < N) { p00 = rowptr[n0]; d0 = rowptr[n0 + 1] - p00; }
  if (n1 < N) { p01 = rowptr[n1]; d1 = rowptr[n1 + 1] - p01; }
  if (n2 < N) { p02 = rowptr[n2]; d2 = rowptr[n2 + 1] - p02; }
  if (n3 < N) { p03 = rowptr[n3]; d3 = rowptr[n3 + 1] - p03; }
  float* wl0 = wlds[wv][0]; float* wl1 = wlds[wv][1];
  float* wl2 = wlds[wv][2]; float* wl3 = wlds[wv][3];
  int* sd0 = slds[wv][0]; int* sd1 = slds[wv][1];
  int* sd2 = slds[wv][2]; int* sd3 = slds[wv][3];

  if (d0 > 64 || d1 > 64 || d2 > 64 || d3 > 64) {
    // rare fallback: whole-wave per node, with max
    for (int q = 0; q < 4; ++q) {
      int n = q == 0 ? n0 : q == 1 ? n1 : q == 2 ? n2 : n3;
      if (n >= N) continue;
      int p0 = q == 0 ? p00 : q == 1 ? p01 : q == 2 ? p02 : p03;
      int deg = q == 0 ? d0 : q == 1 ? d1 : q == 2 ? d2 : d3;
      float acc = 0.f;
      if (deg > 0) {
        int p1 = p0 + deg;
        float ern = er[n];
        float m = -3.4e38f;
        for (int i = p0 + lane; i < p1; i += 64)
          m = fmaxf(m, lrelu(el[srcs[i]] + ern));
        #pragma unroll
        for (int st = 1; st <= 32; st <<= 1) m = fmaxf(m, __shfl_xor(m, st));
        float z = 0.f;
        for (int i = p0 + lane; i < p1; i += 64)
          z += __expf(lrelu(el[srcs[i]] + ern) - m);
        #pragma unroll
        for (int st = 1; st <= 32; st <<= 1) z += __shfl_xor(z, st);
        float iz = 1.f / z;
        for (int i = p0; i < p1; ++i) {
          int s0 = srcs[i];
          float w = __expf(lrelu(el[s0] + ern) - m) * iz;
          acc = fmaf(feat[(size_t)s0 * 64 + lane], w, acc);
        }
      }
      out[(size_t)n * 64 + lane] = acc + bias[lane];
    }
    return;
  }
  // fast path: stage unnormalized weights per node; iz kept in registers
  auto stage = [&](int n, int p0, int d, float* wl, int* sd) -> float {
    if (n >= N || d <= 0) return 0.f;
    float ern = er[n];
    float w = 0.f;
    if (lane < d) {
      int s = srcs[p0 + lane];
      sd[lane] = s;
      w = __expf(lrelu(el[s] + ern));
    }
    wl[lane] = w;
    float z = w;
    #pragma unroll
    for (int st = 1; st <= 32; st <<= 1) z += __shfl_xor(z, st);
    return 1.f / z;
  };
  float iz0 = stage(n0, p00, d0, wl0, sd0);
  float iz1 = stage(n1, p01, d1, wl1, sd1);
  float iz2 = stage(n2, p02, d2, wl2, sd2);
  float iz3 = stage(n3, p03, d3, wl3, sd3);
  asm volatile("s_waitcnt lgkmcnt(0)" ::: "memory");
  float a0 = 0.f, a1 = 0.f, a2 = 0.f, a3 = 0.f;
  int dmax = max(max(d0, d1), max(d2, d3));
  for (int i = 0; i < dmax; ++i) {
    if (i < d0) a0 = fmaf(feat[(size_t)sd0[i] * 64 + lane], wl0[i], a0);
    if (i < d1) a1 = fmaf(feat[(size_t)sd1[i] * 64 + lane], wl1[i], a1);
    if (i < d2) a2 = fmaf(feat[(size_t)sd2[i] * 64 + lane], wl2[i], a2);
    if (i < d3) a3 = fmaf(feat[(size_t)sd3[i] * 64 + lane], wl3[i], a3);
  }
  float bv = bias[lane];
  if (n0 < N) out[(size_t)n0 * 64 + lane] = a0 * iz0 + bv;
  if (n1 < N) out[(size_t)n1 * 64 + lane] = a1 * iz1 + bv;
  if (n2 < N) out[(size_t)n2 * 64 + lane] = a2 * iz2 + bv;
  if (n3 < N) out[(size_t)n3 * 64 + lane] = a3 * iz3 + bv;
}

extern "C" void kernel_launch(void* const* d_in, const int* in_sizes, int n_in,
                              void* d_out, int out_size, void* d_ws, size_t ws_size,
                              hipStream_t stream) {
  const float* x   = (const float*)d_in[0];
  const int*   src = (const int*)d_in[1];
  const int*   dst = (const int*)d_in[2];
  const float* W1  = (const float*)d_in[3];
  const float* al1 = (const float*)d_in[4];
  const float* ar1 = (const float*)d_in[5];
  const float* b1  = (const float*)d_in[6];
  const float* W2  = (const float*)d_in[7];
  const float* al2 = (const float*)d_in[8];
  const float* ar2 = (const float*)d_in[9];
  const float* b2  = (const float*)d_in[10];
  float* out = (float*)d_out;

  char* p = (char*)d_ws;
  auto alloc = [&](size_t bytes) { void* r = (void*)p; p += (bytes + 255) & ~(size_t)255; return r; };
  unsigned short* xb    = (unsigned short*)alloc((size_t)NN * 128 * 2);   // 12.8 MB
  unsigned short* w1t   = (unsigned short*)alloc((size_t)512 * 128 * 2);
  unsigned short* w2t   = (unsigned short*)alloc((size_t)64 * 512 * 2);
  unsigned short* walb  = (unsigned short*)alloc((size_t)16 * 128 * 2);
  unsigned short* xagg  = (unsigned short*)alloc((size_t)NN * 1024 * 2);  // 102.4 MB
  unsigned short* out1e = (unsigned short*)alloc((size_t)NN * 512 * 2);   // 51.2 MB
  float* el1   = (float*)alloc((size_t)NN * 8 * 4);
  float* er1   = (float*)alloc((size_t)NN * 8 * 4);
  float* feat2 = (float*)alloc((size_t)NN * 64 * 4);
  float* el2   = (float*)alloc((size_t)NN * 4);
  float* er2   = (float*)alloc((size_t)NN * 4);
  int* rowptr  = (int*)alloc((size_t)(NN + 1) * 4);
  int* srcs    = (int*)alloc((size_t)NE * 4);
  int* cnt     = (int*)alloc((size_t)NN * 4);
  int* fill    = (int*)alloc((size_t)NN * 4);

  hipMemsetAsync(cnt, 0, (size_t)NN * 4, stream);
  hipMemsetAsync(fill, 0, (size_t)NN * 4, stream);

  // prep (cvt_x + W transposes + walb + hist)
  prep_all_kernel<<<(1700352 + 255) / 256, 256, 0, stream>>>(
      x, xb, W1, W2, al1, ar1, w1t, w2t, walb, dst, cnt);

  // CSR
  scan_kernel<<<1, 1024, 0, stream>>>(cnt, rowptr, NN);
  scatter_kernel<<<(NE + 255) / 256, 256, 0, stream>>>(dst, src, rowptr, fill, srcs, NE);

  // layer 1 (linearity-reordered)
  eler_kernel<<<(NN + 63) / 64, 256, 0, stream>>>(xb, walb, el1, er1);
  aggx_kernel<<<(NN + 7) / 8, 256, 0, stream>>>(xb, el1, er1, srcs, rowptr, xagg, NN);
  gemm1b_mfma<<<dim3((NN + 127) / 128, 8), 256, 0, stream>>>(xagg, w1t, b1, out1e);

  // layer 2
  gemm2_mfma<<<(NN + 127) / 128, 256, 0, stream>>>(out1e, w2t, al2, ar2, feat2, el2, er2);
  agg2f_kernel<<<(NN + 15) / 16, 256, 0, stream>>>(feat2, el2, er2, srcs, rowptr, b2, out, NN);
}

// Round 17
// 279.724 us; speedup vs baseline: 1.4984x; 1.3343x over previous
//
#include <hip/hip_runtime.h>
#include <cstdint>

// GAT 2-layer: N=50000, E=800000.
// Layer 1 via linearity: aggregate x (256B bf16 rows), then batched per-head
// MFMA GEMM. aggx & agg2f: 2 nodes/wave (proven equilibrium), no-max softmax.
// CSR scan: multiblock coalesced (3 tiny kernels) instead of 1-CU serial.
#define NN 50000
#define NE 800000

typedef short bf16x8 __attribute__((ext_vector_type(8)));
typedef float f32x4 __attribute__((ext_vector_type(4)));
typedef float f32x2 __attribute__((ext_vector_type(2)));

__device__ __forceinline__ float lrelu(float x) { return x > 0.f ? x : 0.2f * x; }
__device__ __forceinline__ float elu(float x) { return x > 0.f ? x : __expf(x) - 1.f; }
__device__ __forceinline__ unsigned short f2bf(float f) {
  unsigned u = __float_as_uint(f);
  unsigned r = (u + 0x7FFFu + ((u >> 16) & 1u)) >> 16;   // RNE
  return (unsigned short)r;
}
__device__ __forceinline__ f32x2 fma2(f32x2 a, f32x2 b, f32x2 c) {
#if __has_builtin(__builtin_elementwise_fma)
  return __builtin_elementwise_fma(a, b, c);
#else
  f32x2 r; r[0] = fmaf(a[0], b[0], c[0]); r[1] = fmaf(a[1], b[1], c[1]); return r;
#endif
}

// ===================== prep (fused cvt_x + w-transposes + walb + hist) ======
__global__ __launch_bounds__(256)
void prep_all_kernel(const float* __restrict__ x, unsigned short* __restrict__ xb,
                     const float* __restrict__ W1, const float* __restrict__ W2,
                     const float* __restrict__ al, const float* __restrict__ ar,
                     unsigned short* __restrict__ w1t, unsigned short* __restrict__ w2t,
                     unsigned short* __restrict__ walb,
                     const int* __restrict__ dst, int* __restrict__ cnt) {
  int idx = blockIdx.x * 256 + threadIdx.x;
  if (idx < 800000) {                          // cvt_x: 8 elems each
    float4 a = *(const float4*)(x + (size_t)idx * 8);
    float4 b = *(const float4*)(x + (size_t)idx * 8 + 4);
    unsigned short us[8] = { f2bf(a.x), f2bf(a.y), f2bf(a.z), f2bf(a.w),
                             f2bf(b.x), f2bf(b.y), f2bf(b.z), f2bf(b.w) };
    *(uint4*)(xb + (size_t)idx * 8) = *(const uint4*)us;
  } else if (idx < 865536) {                   // W1 -> w1t [512][128]
    int t = idx - 800000;
    int k = t >> 9, c = t & 511;
    w1t[(size_t)c * 128 + k] = f2bf(W1[t]);
  } else if (idx < 898304) {                   // W2 -> w2t [64][512]
    int t = idx - 865536;
    int k = t >> 6, c = t & 63;
    w2t[(size_t)c * 512 + k] = f2bf(W2[t]);
  } else if (idx < 900352) {                   // walb [16][128]
    int t = idx - 898304;
    int k = t >> 4, o = t & 15, h = o & 7;
    const float* a = (o < 8) ? al : ar;
    float s = 0.f;
    #pragma unroll 8
    for (int d = 0; d < 64; ++d)
      s += W1[(size_t)k * 512 + h * 64 + d] * a[h * 64 + d];
    walb[o * 128 + k] = f2bf(s);
  } else if (idx < 1700352) {                  // hist
    int e = idx - 900352;
    atomicAdd(&cnt[dst[e]], 1);
  }
}

// ===== eler: el1/er1 [N,8] = xb @ walb^T via MFMA, 16 nodes/wave ============
__global__ __launch_bounds__(256)
void eler_kernel(const unsigned short* __restrict__ xb,    // [NN][128]
                 const unsigned short* __restrict__ walb,  // [16][128]
                 float* __restrict__ el, float* __restrict__ er) {
  int wv = threadIdx.x >> 6, lane = threadIdx.x & 63;
  int row0 = blockIdx.x * 64 + wv * 16;
  const int l15 = lane & 15, kg = lane >> 4;
  f32x4 c = {0.f, 0.f, 0.f, 0.f};
  #pragma unroll
  for (int ks = 0; ks < 4; ++ks) {
    bf16x8 a = {};
    int row = row0 + l15;
    if (row < NN) a = *(const bf16x8*)(xb + (size_t)row * 128 + ks * 32 + kg * 8);
    bf16x8 b = *(const bf16x8*)(walb + (size_t)l15 * 128 + ks * 32 + kg * 8);
    c = __builtin_amdgcn_mfma_f32_16x16x32_bf16(a, b, c, 0, 0, 0);
  }
  #pragma unroll
  for (int r = 0; r < 4; ++r) {
    int row = row0 + kg * 4 + r;
    if (row < NN) {
      if (l15 < 8) el[(size_t)row * 8 + l15] = c[r];
      else         er[(size_t)row * 8 + (l15 - 8)] = c[r];
    }
  }
}

// ============== multiblock exclusive scan: cnt[NN] -> rowptr =================
__global__ __launch_bounds__(512)
void scan1_kernel(const int* __restrict__ cnt, int* __restrict__ rowptr,
                  int* __restrict__ bsum, int N) {
  __shared__ int s[512];
  int t = threadIdx.x;
  int i = blockIdx.x * 512 + t;
  int v = (i < N) ? cnt[i] : 0;
  s[t] = v;
  __syncthreads();
  #pragma unroll
  for (int d = 1; d < 512; d <<= 1) {
    int u = (t >= d) ? s[t - d] : 0;
    __syncthreads();
    s[t] += u;
    __syncthreads();
  }
  if (i < N) rowptr[i] = s[t] - v;      // local exclusive
  if (t == 511) bsum[blockIdx.x] = s[511];
}

__global__ __launch_bounds__(128)
void scan2_kernel(int* __restrict__ bsum, int* __restrict__ boff, int nb) {
  // tiny: single thread serial scan of nb (<=128) block sums
  if (threadIdx.x == 0) {
    int run = 0;
    for (int i = 0; i < nb; ++i) { boff[i] = run; run += bsum[i]; }
  }
}

__global__ __launch_bounds__(512)
void scan3_kernel(int* __restrict__ rowptr, const int* __restrict__ boff, int N) {
  int i = blockIdx.x * 512 + threadIdx.x;
  if (i < N) rowptr[i] += boff[blockIdx.x];
  if (i == 0) rowptr[N] = NE;           // total edge count is a constant
}

__global__ void scatter_kernel(const int* __restrict__ dst, const int* __restrict__ src,
                               const int* __restrict__ rowptr, int* __restrict__ fill,
                               int* __restrict__ srcs, int E) {
  int e = blockIdx.x * 256 + threadIdx.x;
  if (e >= E) return;
  int d = dst[e];
  int pos = atomicAdd(&fill[d], 1);
  srcs[rowptr[d] + pos] = src[e];
}

// ==== aggx: xagg[n,h,:] = sum_e alpha_e,h * xb[src_e,:]; 2 nodes per wave ====
__global__ __launch_bounds__(256)
void aggx_kernel(const unsigned short* __restrict__ xb,
                 const float* __restrict__ el, const float* __restrict__ er,
                 const int* __restrict__ srcs, const int* __restrict__ rowptr,
                 unsigned short* __restrict__ xagg, int N) {
  __shared__ float wlds[4][2][64 * 8];
  __shared__ int slds[4][2][64];
  __shared__ float mzlds[4][2][8];
  int wv = threadIdx.x >> 6;
  int lane = threadIdx.x & 63;
  const int myh = lane >> 3, j = lane & 7;
  int n0 = blockIdx.x * 8 + wv * 2, n1 = n0 + 1;
  bool v0 = n0 < N, v1 = n1 < N;
  int p00 = 0, d0 = 0, p01 = 0, d1 = 0;
  if (v0) { p00 = rowptr[n0]; d0 = rowptr[n0 + 1] - p00; }
  if (v1) { p01 = rowptr[n1]; d1 = rowptr[n1 + 1] - p01; }
  float* wl0 = wlds[wv][0]; float* wl1 = wlds[wv][1];
  int* sd0 = slds[wv][0];   int* sd1 = slds[wv][1];
  float* mz0 = mzlds[wv][0]; float* mz1 = mzlds[wv][1];

  if (d0 > 64 || d1 > 64) {
    // ---- rare fallback: whole-wave per node, 3-pass chunked with max ----
    for (int q = 0; q < 2; ++q) {
      int n = q ? n1 : n0;
      if (n >= N) continue;
      int p0 = q ? p01 : p00;
      int deg = q ? d1 : d0;
      f32x2 a00 = {0.f, 0.f}, a01 = a00, a10 = a00, a11 = a00;
      f32x2 a20 = a00, a21 = a00, a30 = a00, a31 = a00;
      if (deg > 0) {
        int p1 = p0 + deg;
        float er8[8];
        *(float4*)&er8[0] = *(const float4*)(er + (size_t)n * 8);
        *(float4*)&er8[4] = *(const float4*)(er + (size_t)n * 8 + 4);
        float erh = er8[0];
        #pragma unroll
        for (int h = 1; h < 8; ++h) erh = (myh == h) ? er8[h] : erh;
        float m = -3.4e38f;
        for (int i = p0 + j; i < p1; i += 8)
          m = fmaxf(m, lrelu(el[(size_t)srcs[i] * 8 + myh] + erh));
        m = fmaxf(m, __shfl_xor(m, 1));
        m = fmaxf(m, __shfl_xor(m, 2));
        m = fmaxf(m, __shfl_xor(m, 4));
        float z = 0.f;
        for (int i = p0 + j; i < p1; i += 8)
          z += __expf(lrelu(el[(size_t)srcs[i] * 8 + myh] + erh) - m);
        z += __shfl_xor(z, 1); z += __shfl_xor(z, 2); z += __shfl_xor(z, 4);
        if (j == 0) { mz0[myh] = m; mz1[myh] = 1.f / z; }
        asm volatile("s_waitcnt lgkmcnt(0)" ::: "memory");
        float m8[8];
        #pragma unroll
        for (int h = 0; h < 8; ++h) m8[h] = mz0[h];
        for (int c0 = p0; c0 < p1; c0 += 64) {
          int cnt = min(64, p1 - c0);
          if (lane < cnt) {
            int s = srcs[c0 + lane];
            sd0[lane] = s;
            float elr[8];
            *(float4*)&elr[0] = *(const float4*)(el + (size_t)s * 8);
            *(float4*)&elr[4] = *(const float4*)(el + (size_t)s * 8 + 4);
            #pragma unroll
            for (int h = 0; h < 8; ++h)
              wl0[lane * 8 + h] = __expf(lrelu(elr[h] + er8[h]) - m8[h]);
          }
          asm volatile("s_waitcnt lgkmcnt(0)" ::: "memory");
          for (int i = 0; i < cnt; ++i) {
            int s2 = sd0[i];
            unsigned u = *(const unsigned*)(xb + (size_t)s2 * 128 + lane * 2);
            float4 wa = *(const float4*)&wl0[i * 8];
            float4 wb = *(const float4*)&wl0[i * 8 + 4];
            f32x2 lod, hid;
            lod[0] = lod[1] = __uint_as_float(u << 16);
            hid[0] = hid[1] = __uint_as_float(u & 0xFFFF0000u);
            f32x2 w01, w23, w45, w67;
            w01[0] = wa.x; w01[1] = wa.y; w23[0] = wa.z; w23[1] = wa.w;
            w45[0] = wb.x; w45[1] = wb.y; w67[0] = wb.z; w67[1] = wb.w;
            a00 = fma2(w01, lod, a00); a01 = fma2(w01, hid, a01);
            a10 = fma2(w23, lod, a10); a11 = fma2(w23, hid, a11);
            a20 = fma2(w45, lod, a20); a21 = fma2(w45, hid, a21);
            a30 = fma2(w67, lod, a30); a31 = fma2(w67, hid, a31);
          }
          asm volatile("s_waitcnt lgkmcnt(0)" ::: "memory");
        }
        float iz8[8];
        #pragma unroll
        for (int h = 0; h < 8; ++h) iz8[h] = mz1[h];
        f32x2 s01, s23, s45, s67;
        s01[0] = iz8[0]; s01[1] = iz8[1]; s23[0] = iz8[2]; s23[1] = iz8[3];
        s45[0] = iz8[4]; s45[1] = iz8[5]; s67[0] = iz8[6]; s67[1] = iz8[7];
        a00 *= s01; a01 *= s01; a10 *= s23; a11 *= s23;
        a20 *= s45; a21 *= s45; a30 *= s67; a31 *= s67;
      }
      unsigned short* op = xagg + (size_t)n * 1024;
      unsigned pk;
      pk = (unsigned)f2bf(a00[0]) | ((unsigned)f2bf(a01[0]) << 16);
      *(unsigned*)(op + 0 * 128 + lane * 2) = pk;
      pk = (unsigned)f2bf(a00[1]) | ((unsigned)f2bf(a01[1]) << 16);
      *(unsigned*)(op + 1 * 128 + lane * 2) = pk;
      pk = (unsigned)f2bf(a10[0]) | ((unsigned)f2bf(a11[0]) << 16);
      *(unsigned*)(op + 2 * 128 + lane * 2) = pk;
      pk = (unsigned)f2bf(a10[1]) | ((unsigned)f2bf(a11[1]) << 16);
      *(unsigned*)(op + 3 * 128 + lane * 2) = pk;
      pk = (unsigned)f2bf(a20[0]) | ((unsigned)f2bf(a21[0]) << 16);
      *(unsigned*)(op + 4 * 128 + lane * 2) = pk;
      pk = (unsigned)f2bf(a20[1]) | ((unsigned)f2bf(a21[1]) << 16);
      *(unsigned*)(op + 5 * 128 + lane * 2) = pk;
      pk = (unsigned)f2bf(a30[0]) | ((unsigned)f2bf(a31[0]) << 16);
      *(unsigned*)(op + 6 * 128 + lane * 2) = pk;
      pk = (unsigned)f2bf(a30[1]) | ((unsigned)f2bf(a31[1]) << 16);
      *(unsigned*)(op + 7 * 128 + lane * 2) = pk;
    }
    return;
  }

  // ---- fast path: no-max softmax, 2 nodes interleaved ----
  if (v0 && d0 > 0) {
    float er8[8];
    *(float4*)&er8[0] = *(const float4*)(er + (size_t)n0 * 8);
    *(float4*)&er8[4] = *(const float4*)(er + (size_t)n0 * 8 + 4);
    float w8[8] = {0.f, 0.f, 0.f, 0.f, 0.f, 0.f, 0.f, 0.f};
    if (lane < d0) {
      int s = srcs[p00 + lane];
      sd0[lane] = s;
      float elr[8];
      *(float4*)&elr[0] = *(const float4*)(el + (size_t)s * 8);
      *(float4*)&elr[4] = *(const float4*)(el + (size_t)s * 8 + 4);
      #pragma unroll
      for (int h = 0; h < 8; ++h) w8[h] = __expf(lrelu(elr[h] + er8[h]));
    }
    #pragma unroll
    for (int h = 0; h < 8; ++h) wl0[lane * 8 + h] = w8[h];
  }
  if (v1 && d1 > 0) {
    float er8[8];
    *(float4*)&er8[0] = *(const float4*)(er + (size_t)n1 * 8);
    *(float4*)&er8[4] = *(const float4*)(er + (size_t)n1 * 8 + 4);
    float w8[8] = {0.f, 0.f, 0.f, 0.f, 0.f, 0.f, 0.f, 0.f};
    if (lane < d1) {
      int s = srcs[p01 + lane];
      sd1[lane] = s;
      float elr[8];
      *(float4*)&elr[0] = *(const float4*)(el + (size_t)s * 8);
      *(float4*)&elr[4] = *(const float4*)(el + (size_t)s * 8 + 4);
      #pragma unroll
      for (int h = 0; h < 8; ++h) w8[h] = __expf(lrelu(elr[h] + er8[h]));
    }
    #pragma unroll
    for (int h = 0; h < 8; ++h) wl1[lane * 8 + h] = w8[h];
  }
  asm volatile("s_waitcnt lgkmcnt(0)" ::: "memory");
  // z-reduce per node: roles (myh, j): 8 strided reads + 3 shfl
  if (v0 && d0 > 0) {
    float z = 0.f;
    #pragma unroll
    for (int t2 = 0; t2 < 8; ++t2) z += wl0[(t2 * 8 + j) * 8 + myh];
    z += __shfl_xor(z, 1); z += __shfl_xor(z, 2); z += __shfl_xor(z, 4);
    if (j == 0) mz0[myh] = 1.f / z;
  }
  if (v1 && d1 > 0) {
    float z = 0.f;
    #pragma unroll
    for (int t2 = 0; t2 < 8; ++t2) z += wl1[(t2 * 8 + j) * 8 + myh];
    z += __shfl_xor(z, 1); z += __shfl_xor(z, 2); z += __shfl_xor(z, 4);
    if (j == 0) mz1[myh] = 1.f / z;
  }
  asm volatile("s_waitcnt lgkmcnt(0)" ::: "memory");
  // interleaved aggregation: two independent chains
  f32x2 aA00 = {0.f, 0.f}, aA01 = aA00, aA10 = aA00, aA11 = aA00;
  f32x2 aA20 = aA00, aA21 = aA00, aA30 = aA00, aA31 = aA00;
  f32x2 aB00 = aA00, aB01 = aA00, aB10 = aA00, aB11 = aA00;
  f32x2 aB20 = aA00, aB21 = aA00, aB30 = aA00, aB31 = aA00;
  auto stepA = [&](int i) {
    int s2 = sd0[i];
    unsigned u = *(const unsigned*)(xb + (size_t)s2 * 128 + lane * 2);
    float4 wa = *(const float4*)&wl0[i * 8];
    float4 wb = *(const float4*)&wl0[i * 8 + 4];
    f32x2 lod, hid;
    lod[0] = lod[1] = __uint_as_float(u << 16);
    hid[0] = hid[1] = __uint_as_float(u & 0xFFFF0000u);
    f32x2 w01, w23, w45, w67;
    w01[0] = wa.x; w01[1] = wa.y; w23[0] = wa.z; w23[1] = wa.w;
    w45[0] = wb.x; w45[1] = wb.y; w67[0] = wb.z; w67[1] = wb.w;
    aA00 = fma2(w01, lod, aA00); aA01 = fma2(w01, hid, aA01);
    aA10 = fma2(w23, lod, aA10); aA11 = fma2(w23, hid, aA11);
    aA20 = fma2(w45, lod, aA20); aA21 = fma2(w45, hid, aA21);
    aA30 = fma2(w67, lod, aA30); aA31 = fma2(w67, hid, aA31);
  };
  auto stepB = [&](int i) {
    int s2 = sd1[i];
    unsigned u = *(const unsigned*)(xb + (size_t)s2 * 128 + lane * 2);
    float4 wa = *(const float4*)&wl1[i * 8];
    float4 wb = *(const float4*)&wl1[i * 8 + 4];
    f32x2 lod, hid;
    lod[0] = lod[1] = __uint_as_float(u << 16);
    hid[0] = hid[1] = __uint_as_float(u & 0xFFFF0000u);
    f32x2 w01, w23, w45, w67;
    w01[0] = wa.x; w01[1] = wa.y; w23[0] = wa.z; w23[1] = wa.w;
    w45[0] = wb.x; w45[1] = wb.y; w67[0] = wb.z; w67[1] = wb.w;
    aB00 = fma2(w01, lod, aB00); aB01 = fma2(w01, hid, aB01);
    aB10 = fma2(w23, lod, aB10); aB11 = fma2(w23, hid, aB11);
    aB20 = fma2(w45, lod, aB20); aB21 = fma2(w45, hid, aB21);
    aB30 = fma2(w67, lod, aB30); aB31 = fma2(w67, hid, aB31);
  };
  int dmin = min(d0, d1);
  int i = 0;
  for (; i < dmin; ++i) { stepA(i); stepB(i); }
  for (int k = i; k < d0; ++k) stepA(k);
  for (int k = i; k < d1; ++k) stepB(k);
  // scale by 1/z and store
  if (v0) {
    if (d0 > 0) {
      float iz[8];
      #pragma unroll
      for (int h = 0; h < 8; ++h) iz[h] = mz0[h];
      f32x2 s01, s23, s45, s67;
      s01[0] = iz[0]; s01[1] = iz[1]; s23[0] = iz[2]; s23[1] = iz[3];
      s45[0] = iz[4]; s45[1] = iz[5]; s67[0] = iz[6]; s67[1] = iz[7];
      aA00 *= s01; aA01 *= s01; aA10 *= s23; aA11 *= s23;
      aA20 *= s45; aA21 *= s45; aA30 *= s67; aA31 *= s67;
    }
    unsigned short* op = xagg + (size_t)n0 * 1024;
    unsigned pk;
    pk = (unsigned)f2bf(aA00[0]) | ((unsigned)f2bf(aA01[0]) << 16);
    *(unsigned*)(op + 0 * 128 + lane * 2) = pk;
    pk = (unsigned)f2bf(aA00[1]) | ((unsigned)f2bf(aA01[1]) << 16);
    *(unsigned*)(op + 1 * 128 + lane * 2) = pk;
    pk = (unsigned)f2bf(aA10[0]) | ((unsigned)f2bf(aA11[0]) << 16);
    *(unsigned*)(op + 2 * 128 + lane * 2) = pk;
    pk = (unsigned)f2bf(aA10[1]) | ((unsigned)f2bf(aA11[1]) << 16);
    *(unsigned*)(op + 3 * 128 + lane * 2) = pk;
    pk = (unsigned)f2bf(aA20[0]) | ((unsigned)f2bf(aA21[0]) << 16);
    *(unsigned*)(op + 4 * 128 + lane * 2) = pk;
    pk = (unsigned)f2bf(aA20[1]) | ((unsigned)f2bf(aA21[1]) << 16);
    *(unsigned*)(op + 5 * 128 + lane * 2) = pk;
    pk = (unsigned)f2bf(aA30[0]) | ((unsigned)f2bf(aA31[0]) << 16);
    *(unsigned*)(op + 6 * 128 + lane * 2) = pk;
    pk = (unsigned)f2bf(aA30[1]) | ((unsigned)f2bf(aA31[1]) << 16);
    *(unsigned*)(op + 7 * 128 + lane * 2) = pk;
  }
  if (v1) {
    if (d1 > 0) {
      float iz[8];
      #pragma unroll
      for (int h = 0; h < 8; ++h) iz[h] = mz1[h];
      f32x2 s01, s23, s45, s67;
      s01[0] = iz[0]; s01[1] = iz[1]; s23[0] = iz[2]; s23[1] = iz[3];
      s45[0] = iz[4]; s45[1] = iz[5]; s67[0] = iz[6]; s67[1] = iz[7];
      aB00 *= s01; aB01 *= s01; aB10 *= s23; aB11 *= s23;
      aB20 *= s45; aB21 *= s45; aB30 *= s67; aB31 *= s67;
    }
    unsigned short* op = xagg + (size_t)n1 * 1024;
    unsigned pk;
    pk = (unsigned)f2bf(aB00[0]) | ((unsigned)f2bf(aB01[0]) << 16);
    *(unsigned*)(op + 0 * 128 + lane * 2) = pk;
    pk = (unsigned)f2bf(aB00[1]) | ((unsigned)f2bf(aB01[1]) << 16);
    *(unsigned*)(op + 1 * 128 + lane * 2) = pk;
    pk = (unsigned)f2bf(aB10[0]) | ((unsigned)f2bf(aB11[0]) << 16);
    *(unsigned*)(op + 2 * 128 + lane * 2) = pk;
    pk = (unsigned)f2bf(aB10[1]) | ((unsigned)f2bf(aB11[1]) << 16);
    *(unsigned*)(op + 3 * 128 + lane * 2) = pk;
    pk = (unsigned)f2bf(aB20[0]) | ((unsigned)f2bf(aB21[0]) << 16);
    *(unsigned*)(op + 4 * 128 + lane * 2) = pk;
    pk = (unsigned)f2bf(aB20[1]) | ((unsigned)f2bf(aB21[1]) << 16);
    *(unsigned*)(op + 5 * 128 + lane * 2) = pk;
    pk = (unsigned)f2bf(aB30[0]) | ((unsigned)f2bf(aB31[0]) << 16);
    *(unsigned*)(op + 6 * 128 + lane * 2) = pk;
    pk = (unsigned)f2bf(aB30[1]) | ((unsigned)f2bf(aB31[1]) << 16);
    *(unsigned*)(op + 7 * 128 + lane * 2) = pk;
  }
}

// ===== gemm1b: out1e[:, h*64:+64] = elu(xagg[:,h,:] @ W1_h + b1_h), bf16 =====
__global__ __launch_bounds__(256)
void gemm1b_mfma(const unsigned short* __restrict__ A,     // xagg [NN][8][128]
                 const unsigned short* __restrict__ w1t,   // [512][128]
                 const float* __restrict__ bias,           // b1 [512]
                 unsigned short* __restrict__ out) {       // out1e [NN][512]
  __shared__ unsigned short As[128][72];
  __shared__ unsigned short Bs[64][72];
  const int t = threadIdx.x, lane = t & 63, wid = t >> 6;
  const int h = blockIdx.y;
  const int row0 = blockIdx.x * 128;
  const int l15 = lane & 15, kg = lane >> 4;
  f32x4 acc[2][4] = {};
  for (int kk = 0; kk < 128; kk += 64) {
    #pragma unroll
    for (int it = 0; it < 4; ++it) {
      int c = t + it * 256;                 // 1024 chunks A
      int r = c >> 3, kc = (c & 7) * 8;
      uint4 v = make_uint4(0, 0, 0, 0);
      if (row0 + r < NN)
        v = *(const uint4*)(A + (size_t)(row0 + r) * 1024 + h * 128 + kk + kc);
      *(uint4*)&As[r][kc] = v;
    }
    #pragma unroll
    for (int it = 0; it < 2; ++it) {
      int c = t + it * 256;                 // 512 chunks B
      int r = c >> 3, kc = (c & 7) * 8;
      *(uint4*)&Bs[r][kc] = *(const uint4*)(w1t + (size_t)(h * 64 + r) * 128 + kk + kc);
    }
    __syncthreads();
    #pragma unroll
    for (int ks = 0; ks < 2; ++ks) {
      bf16x8 af[2], bfr[4];
      #pragma unroll
      for (int fi = 0; fi < 2; ++fi)
        af[fi] = *(const bf16x8*)&As[wid * 32 + fi * 16 + l15][ks * 32 + kg * 8];
      #pragma unroll
      for (int fj = 0; fj < 4; ++fj)
        bfr[fj] = *(const bf16x8*)&Bs[fj * 16 + l15][ks * 32 + kg * 8];
      #pragma unroll
      for (int fi = 0; fi < 2; ++fi)
        #pragma unroll
        for (int fj = 0; fj < 4; ++fj)
          acc[fi][fj] = __builtin_amdgcn_mfma_f32_16x16x32_bf16(af[fi], bfr[fj], acc[fi][fj], 0, 0, 0);
    }
    __syncthreads();
  }
  float bj[4];
  #pragma unroll
  for (int fj = 0; fj < 4; ++fj) bj[fj] = bias[h * 64 + fj * 16 + l15];
  #pragma unroll
  for (int fi = 0; fi < 2; ++fi) {
    const int rbase = row0 + wid * 32 + fi * 16 + kg * 4;
    #pragma unroll
    for (int r = 0; r < 4; ++r) {
      int row = rbase + r;
      if (row < NN) {
        #pragma unroll
        for (int fj = 0; fj < 4; ++fj)
          out[(size_t)row * 512 + h * 64 + fj * 16 + l15] = f2bf(elu(acc[fi][fj][r] + bj[fj]));
      }
    }
  }
}

// ====== GEMM2 (MFMA): feat2(f32) = out1e @ W2T^T, fused el2/er2 ==============
__global__ __launch_bounds__(256)
void gemm2_mfma(const unsigned short* __restrict__ A,     // out1e [NN][512] bf16
                const unsigned short* __restrict__ w2t,   // [64][512] bf16
                const float* __restrict__ al, const float* __restrict__ ar,
                float* __restrict__ C,                    // feat2 [NN][64] f32
                float* __restrict__ el, float* __restrict__ er) {
  __shared__ unsigned short As[128][72];
  __shared__ unsigned short Bs[64][72];
  const int t = threadIdx.x, lane = t & 63, wid = t >> 6;
  const int row0 = blockIdx.x * 128;
  const int l15 = lane & 15, kg = lane >> 4;
  f32x4 acc[2][4] = {};
  for (int kk = 0; kk < 512; kk += 64) {
    #pragma unroll
    for (int it = 0; it < 4; ++it) {
      int c = t + it * 256;
      int r = c >> 3, kc = (c & 7) * 8;
      uint4 v = make_uint4(0, 0, 0, 0);
      if (row0 + r < NN) v = *(const uint4*)(A + (size_t)(row0 + r) * 512 + kk + kc);
      *(uint4*)&As[r][kc] = v;
    }
    #pragma unroll
    for (int it = 0; it < 2; ++it) {
      int c = t + it * 256;
      int r = c >> 3, kc = (c & 7) * 8;
      *(uint4*)&Bs[r][kc] = *(const uint4*)(w2t + (size_t)r * 512 + kk + kc);
    }
    __syncthreads();
    #pragma unroll
    for (int ks = 0; ks < 2; ++ks) {
      bf16x8 af[2], bfr[4];
      #pragma unroll
      for (int fi = 0; fi < 2; ++fi)
        af[fi] = *(const bf16x8*)&As[wid * 32 + fi * 16 + l15][ks * 32 + kg * 8];
      #pragma unroll
      for (int fj = 0; fj < 4; ++fj)
        bfr[fj] = *(const bf16x8*)&Bs[fj * 16 + l15][ks * 32 + kg * 8];
      #pragma unroll
      for (int fi = 0; fi < 2; ++fi)
        #pragma unroll
        for (int fj = 0; fj < 4; ++fj)
          acc[fi][fj] = __builtin_amdgcn_mfma_f32_16x16x32_bf16(af[fi], bfr[fj], acc[fi][fj], 0, 0, 0);
    }
    __syncthreads();
  }
  float alf[4], arf[4];
  #pragma unroll
  for (int fj = 0; fj < 4; ++fj) { alf[fj] = al[fj * 16 + l15]; arf[fj] = ar[fj * 16 + l15]; }
  #pragma unroll
  for (int fi = 0; fi < 2; ++fi) {
    float pl[4] = {}, pr[4] = {};
    #pragma unroll
    for (int fj = 0; fj < 4; ++fj)
      #pragma unroll
      for (int r = 0; r < 4; ++r) {
        pl[r] = fmaf(acc[fi][fj][r], alf[fj], pl[r]);
        pr[r] = fmaf(acc[fi][fj][r], arf[fj], pr[r]);
      }
    const int rbase = row0 + wid * 32 + fi * 16 + kg * 4;
    #pragma unroll
    for (int r = 0; r < 4; ++r) {
      int row = rbase + r;
      if (row < NN) {
        #pragma unroll
        for (int fj = 0; fj < 4; ++fj) C[(size_t)row * 64 + fj * 16 + l15] = acc[fi][fj][r];
      }
    }
    #pragma unroll
    for (int s = 1; s <= 8; s <<= 1)
      #pragma unroll
      for (int r = 0; r < 4; ++r) {
        pl[r] += __shfl_xor(pl[r], s);
        pr[r] += __shfl_xor(pr[r], s);
      }
    if (l15 == 0) {
      #pragma unroll
      for (int r = 0; r < 4; ++r) {
        int row = rbase + r;
        if (row < NN) { el[row] = pl[r]; er[row] = pr[r]; }
      }
    }
  }
}

// ==== agg2f: single head, 2 nodes per wave, no-max softmax ===================
__global__ __launch_bounds__(256)
void agg2f_kernel(const float* __restrict__ feat,
                  const float* __restrict__ el, const float* __restrict__ er,
                  const int* __restrict__ srcs, const int* __restrict__ rowptr,
                  const float* __restrict__ bias, float* __restrict__ out, int N) {
  __shared__ float wlds[4][2][64];
  __shared__ int slds[4][2][64];
  int wv = threadIdx.x >> 6;
  int lane = threadIdx.x & 63;
  int n0 = blockIdx.x * 8 + wv * 2, n1 = n0 + 1;
  bool v0 = n0 < N, v1 = n1 < N;
  int p00 = 0, d0 = 0, p01 = 0, d1 = 0;
  if (v0) { p00 = rowptr[n0]; d0 = rowptr[n0 + 1] - p00; }
  if (v1) { p01 = rowptr[n1]; d1 = rowptr[n1 + 1] - p01; }
  float* wl0 = wlds[wv][0]; float* wl1 = wlds[wv][1];
  int* sd0 = slds[wv][0];   int* sd1 = slds[wv][1];

  if (d0 > 64 || d1 > 64) {
    // rare fallback: whole-wave per node, with max
    for (int q = 0; q < 2; ++q) {
      int n = q ? n1 : n0;
      if (n >= N) continue;
      int p0 = q ? p01 : p00;
      int deg = q ? d1 : d0;
      float acc = 0.f;
      if (deg > 0) {
        int p1 = p0 + deg;
        float ern = er[n];
        float m = -3.4e38f;
        for (int i = p0 + lane; i < p1; i += 64)
          m = fmaxf(m, lrelu(el[srcs[i]] + ern));
        #pragma unroll
        for (int st = 1; st <= 32; st <<= 1) m = fmaxf(m, __shfl_xor(m, st));
        float z = 0.f;
        for (int i = p0 + lane; i < p1; i += 64)
          z += __expf(lrelu(el[srcs[i]] + ern) - m);
        #pragma unroll
        for (int st = 1; st <= 32; st <<= 1) z += __shfl_xor(z, st);
        float iz = 1.f / z;
        for (int i = p0; i < p1; ++i) {
          int s0 = srcs[i];
          float w = __expf(lrelu(el[s0] + ern) - m) * iz;
          acc = fmaf(feat[(size_t)s0 * 64 + lane], w, acc);
        }
      }
      out[(size_t)n * 64 + lane] = acc + bias[lane];
    }
    return;
  }
  // fast path
  float iz0 = 0.f, iz1 = 0.f;
  if (v0 && d0 > 0) {
    float ern = er[n0];
    float w = 0.f;
    if (lane < d0) {
      int s = srcs[p00 + lane];
      sd0[lane] = s;
      w = __expf(lrelu(el[s] + ern));
    }
    wl0[lane] = w;
    float z = w;
    #pragma unroll
    for (int st = 1; st <= 32; st <<= 1) z += __shfl_xor(z, st);
    iz0 = 1.f / z;
  }
  if (v1 && d1 > 0) {
    float ern = er[n1];
    float w = 0.f;
    if (lane < d1) {
      int s = srcs[p01 + lane];
      sd1[lane] = s;
      w = __expf(lrelu(el[s] + ern));
    }
    wl1[lane] = w;
    float z = w;
    #pragma unroll
    for (int st = 1; st <= 32; st <<= 1) z += __shfl_xor(z, st);
    iz1 = 1.f / z;
  }
  asm volatile("s_waitcnt lgkmcnt(0)" ::: "memory");
  float accA = 0.f, accB = 0.f;
  int dmin = min(d0, d1);
  int i = 0;
  for (; i < dmin; ++i) {
    accA = fmaf(feat[(size_t)sd0[i] * 64 + lane], wl0[i], accA);
    accB = fmaf(feat[(size_t)sd1[i] * 64 + lane], wl1[i], accB);
  }
  for (int k = i; k < d0; ++k)
    accA = fmaf(feat[(size_t)sd0[k] * 64 + lane], wl0[k], accA);
  for (int k = i; k < d1; ++k)
    accB = fmaf(feat[(size_t)sd1[k] * 64 + lane], wl1[k], accB);
  if (v0) out[(size_t)n0 * 64 + lane] = accA * iz0 + bias[lane];
  if (v1) out[(size_t)n1 * 64 + lane] = accB * iz1 + bias[lane];
}

extern "C" void kernel_launch(void* const* d_in, const int* in_sizes, int n_in,
                              void* d_out, int out_size, void* d_ws, size_t ws_size,
                              hipStream_t stream) {
  const float* x   = (const float*)d_in[0];
  const int*   src = (const int*)d_in[1];
  const int*   dst = (const int*)d_in[2];
  const float* W1  = (const float*)d_in[3];
  const float* al1 = (const float*)d_in[4];
  const float* ar1 = (const float*)d_in[5];
  const float* b1  = (const float*)d_in[6];
  const float* W2  = (const float*)d_in[7];
  const float* al2 = (const float*)d_in[8];
  const float* ar2 = (const float*)d_in[9];
  const float* b2  = (const float*)d_in[10];
  float* out = (float*)d_out;

  char* p = (char*)d_ws;
  auto alloc = [&](size_t bytes) { void* r = (void*)p; p += (bytes + 255) & ~(size_t)255; return r; };
  unsigned short* xb    = (unsigned short*)alloc((size_t)NN * 128 * 2);   // 12.8 MB
  unsigned short* w1t   = (unsigned short*)alloc((size_t)512 * 128 * 2);
  unsigned short* w2t   = (unsigned short*)alloc((size_t)64 * 512 * 2);
  unsigned short* walb  = (unsigned short*)alloc((size_t)16 * 128 * 2);
  unsigned short* xagg  = (unsigned short*)alloc((size_t)NN * 1024 * 2);  // 102.4 MB
  unsigned short* out1e = (unsigned short*)alloc((size_t)NN * 512 * 2);   // 51.2 MB
  float* el1   = (float*)alloc((size_t)NN * 8 * 4);
  float* er1   = (float*)alloc((size_t)NN * 8 * 4);
  float* feat2 = (float*)alloc((size_t)NN * 64 * 4);
  float* el2   = (float*)alloc((size_t)NN * 4);
  float* er2   = (float*)alloc((size_t)NN * 4);
  int* rowptr  = (int*)alloc((size_t)(NN + 1) * 4);
  int* srcs    = (int*)alloc((size_t)NE * 4);
  int* cnt     = (int*)alloc((size_t)NN * 4);
  int* fill    = (int*)alloc((size_t)NN * 4);
  int* bsum    = (int*)alloc((size_t)128 * 4);
  int* boff    = (int*)alloc((size_t)128 * 4);

  hipMemsetAsync(cnt, 0, (size_t)NN * 4, stream);
  hipMemsetAsync(fill, 0, (size_t)NN * 4, stream);

  // prep (cvt_x + W transposes + walb + hist)
  prep_all_kernel<<<(1700352 + 255) / 256, 256, 0, stream>>>(
      x, xb, W1, W2, al1, ar1, w1t, w2t, walb, dst, cnt);

  // CSR: multiblock scan + scatter
  const int NB = (NN + 511) / 512;   // 98
  scan1_kernel<<<NB, 512, 0, stream>>>(cnt, rowptr, bsum, NN);
  scan2_kernel<<<1, 128, 0, stream>>>(bsum, boff, NB);
  scan3_kernel<<<NB, 512, 0, stream>>>(rowptr, boff, NN);
  scatter_kernel<<<(NE + 255) / 256, 256, 0, stream>>>(dst, src, rowptr, fill, srcs, NE);

  // layer 1 (linearity-reordered)
  eler_kernel<<<(NN + 63) / 64, 256, 0, stream>>>(xb, walb, el1, er1);
  aggx_kernel<<<(NN + 7) / 8, 256, 0, stream>>>(xb, el1, er1, srcs, rowptr, xagg, NN);
  gemm1b_mfma<<<dim3((NN + 127) / 128, 8), 256, 0, stream>>>(xagg, w1t, b1, out1e);

  // layer 2
  gemm2_mfma<<<(NN + 127) / 128, 256, 0, stream>>>(out1e, w2t, al2, ar2, feat2, el2, er2);
  agg2f_kernel<<<(NN + 7) / 8, 256, 0, stream>>>(feat2, el2, er2, srcs, rowptr, b2, out, NN);
}

// Round 18
// 273.446 us; speedup vs baseline: 1.5329x; 1.0230x over previous
//
#include <hip/hip_runtime.h>
#include <cstdint>

// GAT 2-layer: N=50000, E=800000.
// Layer 1 via linearity: aggregate x (256B bf16 rows), then batched per-head
// MFMA GEMM. aggx & agg2f: 2 nodes/wave, no-max softmax. Multiblock CSR scan.
// feat2 stored bf16 (halves agg2f gather volume); el2/er2 from exact f32.
#define NN 50000
#define NE 800000

typedef short bf16x8 __attribute__((ext_vector_type(8)));
typedef float f32x4 __attribute__((ext_vector_type(4)));
typedef float f32x2 __attribute__((ext_vector_type(2)));

__device__ __forceinline__ float lrelu(float x) { return x > 0.f ? x : 0.2f * x; }
__device__ __forceinline__ float elu(float x) { return x > 0.f ? x : __expf(x) - 1.f; }
__device__ __forceinline__ unsigned short f2bf(float f) {
  unsigned u = __float_as_uint(f);
  unsigned r = (u + 0x7FFFu + ((u >> 16) & 1u)) >> 16;   // RNE
  return (unsigned short)r;
}
__device__ __forceinline__ float bf2f(unsigned short u) {
  return __uint_as_float((unsigned)u << 16);
}
__device__ __forceinline__ f32x2 fma2(f32x2 a, f32x2 b, f32x2 c) {
#if __has_builtin(__builtin_elementwise_fma)
  return __builtin_elementwise_fma(a, b, c);
#else
  f32x2 r; r[0] = fmaf(a[0], b[0], c[0]); r[1] = fmaf(a[1], b[1], c[1]); return r;
#endif
}

// ===================== prep (fused cvt_x + w-transposes + walb + hist) ======
__global__ __launch_bounds__(256)
void prep_all_kernel(const float* __restrict__ x, unsigned short* __restrict__ xb,
                     const float* __restrict__ W1, const float* __restrict__ W2,
                     const float* __restrict__ al, const float* __restrict__ ar,
                     unsigned short* __restrict__ w1t, unsigned short* __restrict__ w2t,
                     unsigned short* __restrict__ walb,
                     const int* __restrict__ dst, int* __restrict__ cnt) {
  int idx = blockIdx.x * 256 + threadIdx.x;
  if (idx < 800000) {                          // cvt_x: 8 elems each
    float4 a = *(const float4*)(x + (size_t)idx * 8);
    float4 b = *(const float4*)(x + (size_t)idx * 8 + 4);
    unsigned short us[8] = { f2bf(a.x), f2bf(a.y), f2bf(a.z), f2bf(a.w),
                             f2bf(b.x), f2bf(b.y), f2bf(b.z), f2bf(b.w) };
    *(uint4*)(xb + (size_t)idx * 8) = *(const uint4*)us;
  } else if (idx < 865536) {                   // W1 -> w1t [512][128]
    int t = idx - 800000;
    int k = t >> 9, c = t & 511;
    w1t[(size_t)c * 128 + k] = f2bf(W1[t]);
  } else if (idx < 898304) {                   // W2 -> w2t [64][512]
    int t = idx - 865536;
    int k = t >> 6, c = t & 63;
    w2t[(size_t)c * 512 + k] = f2bf(W2[t]);
  } else if (idx < 900352) {                   // walb [16][128]
    int t = idx - 898304;
    int k = t >> 4, o = t & 15, h = o & 7;
    const float* a = (o < 8) ? al : ar;
    float s = 0.f;
    #pragma unroll 8
    for (int d = 0; d < 64; ++d)
      s += W1[(size_t)k * 512 + h * 64 + d] * a[h * 64 + d];
    walb[o * 128 + k] = f2bf(s);
  } else if (idx < 1700352) {                  // hist
    int e = idx - 900352;
    atomicAdd(&cnt[dst[e]], 1);
  }
}

// ===== eler: el1/er1 [N,8] = xb @ walb^T via MFMA, 16 nodes/wave ============
__global__ __launch_bounds__(256)
void eler_kernel(const unsigned short* __restrict__ xb,    // [NN][128]
                 const unsigned short* __restrict__ walb,  // [16][128]
                 float* __restrict__ el, float* __restrict__ er) {
  int wv = threadIdx.x >> 6, lane = threadIdx.x & 63;
  int row0 = blockIdx.x * 64 + wv * 16;
  const int l15 = lane & 15, kg = lane >> 4;
  f32x4 c = {0.f, 0.f, 0.f, 0.f};
  #pragma unroll
  for (int ks = 0; ks < 4; ++ks) {
    bf16x8 a = {};
    int row = row0 + l15;
    if (row < NN) a = *(const bf16x8*)(xb + (size_t)row * 128 + ks * 32 + kg * 8);
    bf16x8 b = *(const bf16x8*)(walb + (size_t)l15 * 128 + ks * 32 + kg * 8);
    c = __builtin_amdgcn_mfma_f32_16x16x32_bf16(a, b, c, 0, 0, 0);
  }
  #pragma unroll
  for (int r = 0; r < 4; ++r) {
    int row = row0 + kg * 4 + r;
    if (row < NN) {
      if (l15 < 8) el[(size_t)row * 8 + l15] = c[r];
      else         er[(size_t)row * 8 + (l15 - 8)] = c[r];
    }
  }
}

// ============== multiblock exclusive scan: cnt[NN] -> rowptr =================
__global__ __launch_bounds__(512)
void scan1_kernel(const int* __restrict__ cnt, int* __restrict__ rowptr,
                  int* __restrict__ bsum, int N) {
  __shared__ int s[512];
  int t = threadIdx.x;
  int i = blockIdx.x * 512 + t;
  int v = (i < N) ? cnt[i] : 0;
  s[t] = v;
  __syncthreads();
  #pragma unroll
  for (int d = 1; d < 512; d <<= 1) {
    int u = (t >= d) ? s[t - d] : 0;
    __syncthreads();
    s[t] += u;
    __syncthreads();
  }
  if (i < N) rowptr[i] = s[t] - v;      // local exclusive
  if (t == 511) bsum[blockIdx.x] = s[511];
}

__global__ __launch_bounds__(128)
void scan2_kernel(int* __restrict__ bsum, int* __restrict__ boff, int nb) {
  if (threadIdx.x == 0) {
    int run = 0;
    for (int i = 0; i < nb; ++i) { boff[i] = run; run += bsum[i]; }
  }
}

__global__ __launch_bounds__(512)
void scan3_kernel(int* __restrict__ rowptr, const int* __restrict__ boff, int N) {
  int i = blockIdx.x * 512 + threadIdx.x;
  if (i < N) rowptr[i] += boff[blockIdx.x];
  if (i == 0) rowptr[N] = NE;           // total edge count is a constant
}

__global__ void scatter_kernel(const int* __restrict__ dst, const int* __restrict__ src,
                               const int* __restrict__ rowptr, int* __restrict__ fill,
                               int* __restrict__ srcs, int E) {
  int e = blockIdx.x * 256 + threadIdx.x;
  if (e >= E) return;
  int d = dst[e];
  int pos = atomicAdd(&fill[d], 1);
  srcs[rowptr[d] + pos] = src[e];
}

// ==== aggx: xagg[n,h,:] = sum_e alpha_e,h * xb[src_e,:]; 2 nodes per wave ====
__global__ __launch_bounds__(256)
void aggx_kernel(const unsigned short* __restrict__ xb,
                 const float* __restrict__ el, const float* __restrict__ er,
                 const int* __restrict__ srcs, const int* __restrict__ rowptr,
                 unsigned short* __restrict__ xagg, int N) {
  __shared__ float wlds[4][2][64 * 8];
  __shared__ int slds[4][2][64];
  __shared__ float mzlds[4][2][8];
  int wv = threadIdx.x >> 6;
  int lane = threadIdx.x & 63;
  const int myh = lane >> 3, j = lane & 7;
  int n0 = blockIdx.x * 8 + wv * 2, n1 = n0 + 1;
  bool v0 = n0 < N, v1 = n1 < N;
  int p00 = 0, d0 = 0, p01 = 0, d1 = 0;
  if (v0) { p00 = rowptr[n0]; d0 = rowptr[n0 + 1] - p00; }
  if (v1) { p01 = rowptr[n1]; d1 = rowptr[n1 + 1] - p01; }
  float* wl0 = wlds[wv][0]; float* wl1 = wlds[wv][1];
  int* sd0 = slds[wv][0];   int* sd1 = slds[wv][1];
  float* mz0 = mzlds[wv][0]; float* mz1 = mzlds[wv][1];

  if (d0 > 64 || d1 > 64) {
    // ---- rare fallback: whole-wave per node, 3-pass chunked with max ----
    for (int q = 0; q < 2; ++q) {
      int n = q ? n1 : n0;
      if (n >= N) continue;
      int p0 = q ? p01 : p00;
      int deg = q ? d1 : d0;
      f32x2 a00 = {0.f, 0.f}, a01 = a00, a10 = a00, a11 = a00;
      f32x2 a20 = a00, a21 = a00, a30 = a00, a31 = a00;
      if (deg > 0) {
        int p1 = p0 + deg;
        float er8[8];
        *(float4*)&er8[0] = *(const float4*)(er + (size_t)n * 8);
        *(float4*)&er8[4] = *(const float4*)(er + (size_t)n * 8 + 4);
        float erh = er8[0];
        #pragma unroll
        for (int h = 1; h < 8; ++h) erh = (myh == h) ? er8[h] : erh;
        float m = -3.4e38f;
        for (int i = p0 + j; i < p1; i += 8)
          m = fmaxf(m, lrelu(el[(size_t)srcs[i] * 8 + myh] + erh));
        m = fmaxf(m, __shfl_xor(m, 1));
        m = fmaxf(m, __shfl_xor(m, 2));
        m = fmaxf(m, __shfl_xor(m, 4));
        float z = 0.f;
        for (int i = p0 + j; i < p1; i += 8)
          z += __expf(lrelu(el[(size_t)srcs[i] * 8 + myh] + erh) - m);
        z += __shfl_xor(z, 1); z += __shfl_xor(z, 2); z += __shfl_xor(z, 4);
        if (j == 0) { mz0[myh] = m; mz1[myh] = 1.f / z; }
        asm volatile("s_waitcnt lgkmcnt(0)" ::: "memory");
        float m8[8];
        #pragma unroll
        for (int h = 0; h < 8; ++h) m8[h] = mz0[h];
        for (int c0 = p0; c0 < p1; c0 += 64) {
          int cnt = min(64, p1 - c0);
          if (lane < cnt) {
            int s = srcs[c0 + lane];
            sd0[lane] = s;
            float elr[8];
            *(float4*)&elr[0] = *(const float4*)(el + (size_t)s * 8);
            *(float4*)&elr[4] = *(const float4*)(el + (size_t)s * 8 + 4);
            #pragma unroll
            for (int h = 0; h < 8; ++h)
              wl0[lane * 8 + h] = __expf(lrelu(elr[h] + er8[h]) - m8[h]);
          }
          asm volatile("s_waitcnt lgkmcnt(0)" ::: "memory");
          for (int i = 0; i < cnt; ++i) {
            int s2 = sd0[i];
            unsigned u = *(const unsigned*)(xb + (size_t)s2 * 128 + lane * 2);
            float4 wa = *(const float4*)&wl0[i * 8];
            float4 wb = *(const float4*)&wl0[i * 8 + 4];
            f32x2 lod, hid;
            lod[0] = lod[1] = __uint_as_float(u << 16);
            hid[0] = hid[1] = __uint_as_float(u & 0xFFFF0000u);
            f32x2 w01, w23, w45, w67;
            w01[0] = wa.x; w01[1] = wa.y; w23[0] = wa.z; w23[1] = wa.w;
            w45[0] = wb.x; w45[1] = wb.y; w67[0] = wb.z; w67[1] = wb.w;
            a00 = fma2(w01, lod, a00); a01 = fma2(w01, hid, a01);
            a10 = fma2(w23, lod, a10); a11 = fma2(w23, hid, a11);
            a20 = fma2(w45, lod, a20); a21 = fma2(w45, hid, a21);
            a30 = fma2(w67, lod, a30); a31 = fma2(w67, hid, a31);
          }
          asm volatile("s_waitcnt lgkmcnt(0)" ::: "memory");
        }
        float iz8[8];
        #pragma unroll
        for (int h = 0; h < 8; ++h) iz8[h] = mz1[h];
        f32x2 s01, s23, s45, s67;
        s01[0] = iz8[0]; s01[1] = iz8[1]; s23[0] = iz8[2]; s23[1] = iz8[3];
        s45[0] = iz8[4]; s45[1] = iz8[5]; s67[0] = iz8[6]; s67[1] = iz8[7];
        a00 *= s01; a01 *= s01; a10 *= s23; a11 *= s23;
        a20 *= s45; a21 *= s45; a30 *= s67; a31 *= s67;
      }
      unsigned short* op = xagg + (size_t)n * 1024;
      unsigned pk;
      pk = (unsigned)f2bf(a00[0]) | ((unsigned)f2bf(a01[0]) << 16);
      *(unsigned*)(op + 0 * 128 + lane * 2) = pk;
      pk = (unsigned)f2bf(a00[1]) | ((unsigned)f2bf(a01[1]) << 16);
      *(unsigned*)(op + 1 * 128 + lane * 2) = pk;
      pk = (unsigned)f2bf(a10[0]) | ((unsigned)f2bf(a11[0]) << 16);
      *(unsigned*)(op + 2 * 128 + lane * 2) = pk;
      pk = (unsigned)f2bf(a10[1]) | ((unsigned)f2bf(a11[1]) << 16);
      *(unsigned*)(op + 3 * 128 + lane * 2) = pk;
      pk = (unsigned)f2bf(a20[0]) | ((unsigned)f2bf(a21[0]) << 16);
      *(unsigned*)(op + 4 * 128 + lane * 2) = pk;
      pk = (unsigned)f2bf(a20[1]) | ((unsigned)f2bf(a21[1]) << 16);
      *(unsigned*)(op + 5 * 128 + lane * 2) = pk;
      pk = (unsigned)f2bf(a30[0]) | ((unsigned)f2bf(a31[0]) << 16);
      *(unsigned*)(op + 6 * 128 + lane * 2) = pk;
      pk = (unsigned)f2bf(a30[1]) | ((unsigned)f2bf(a31[1]) << 16);
      *(unsigned*)(op + 7 * 128 + lane * 2) = pk;
    }
    return;
  }

  // ---- fast path: no-max softmax, 2 nodes interleaved ----
  if (v0 && d0 > 0) {
    float er8[8];
    *(float4*)&er8[0] = *(const float4*)(er + (size_t)n0 * 8);
    *(float4*)&er8[4] = *(const float4*)(er + (size_t)n0 * 8 + 4);
    float w8[8] = {0.f, 0.f, 0.f, 0.f, 0.f, 0.f, 0.f, 0.f};
    if (lane < d0) {
      int s = srcs[p00 + lane];
      sd0[lane] = s;
      float elr[8];
      *(float4*)&elr[0] = *(const float4*)(el + (size_t)s * 8);
      *(float4*)&elr[4] = *(const float4*)(el + (size_t)s * 8 + 4);
      #pragma unroll
      for (int h = 0; h < 8; ++h) w8[h] = __expf(lrelu(elr[h] + er8[h]));
    }
    #pragma unroll
    for (int h = 0; h < 8; ++h) wl0[lane * 8 + h] = w8[h];
  }
  if (v1 && d1 > 0) {
    float er8[8];
    *(float4*)&er8[0] = *(const float4*)(er + (size_t)n1 * 8);
    *(float4*)&er8[4] = *(const float4*)(er + (size_t)n1 * 8 + 4);
    float w8[8] = {0.f, 0.f, 0.f, 0.f, 0.f, 0.f, 0.f, 0.f};
    if (lane < d1) {
      int s = srcs[p01 + lane];
      sd1[lane] = s;
      float elr[8];
      *(float4*)&elr[0] = *(const float4*)(el + (size_t)s * 8);
      *(float4*)&elr[4] = *(const float4*)(el + (size_t)s * 8 + 4);
      #pragma unroll
      for (int h = 0; h < 8; ++h) w8[h] = __expf(lrelu(elr[h] + er8[h]));
    }
    #pragma unroll
    for (int h = 0; h < 8; ++h) wl1[lane * 8 + h] = w8[h];
  }
  asm volatile("s_waitcnt lgkmcnt(0)" ::: "memory");
  // z-reduce per node: roles (myh, j): 8 strided reads + 3 shfl
  if (v0 && d0 > 0) {
    float z = 0.f;
    #pragma unroll
    for (int t2 = 0; t2 < 8; ++t2) z += wl0[(t2 * 8 + j) * 8 + myh];
    z += __shfl_xor(z, 1); z += __shfl_xor(z, 2); z += __shfl_xor(z, 4);
    if (j == 0) mz0[myh] = 1.f / z;
  }
  if (v1 && d1 > 0) {
    float z = 0.f;
    #pragma unroll
    for (int t2 = 0; t2 < 8; ++t2) z += wl1[(t2 * 8 + j) * 8 + myh];
    z += __shfl_xor(z, 1); z += __shfl_xor(z, 2); z += __shfl_xor(z, 4);
    if (j == 0) mz1[myh] = 1.f / z;
  }
  asm volatile("s_waitcnt lgkmcnt(0)" ::: "memory");
  // interleaved aggregation: two independent chains
  f32x2 aA00 = {0.f, 0.f}, aA01 = aA00, aA10 = aA00, aA11 = aA00;
  f32x2 aA20 = aA00, aA21 = aA00, aA30 = aA00, aA31 = aA00;
  f32x2 aB00 = aA00, aB01 = aA00, aB10 = aA00, aB11 = aA00;
  f32x2 aB20 = aA00, aB21 = aA00, aB30 = aA00, aB31 = aA00;
  auto stepA = [&](int i) {
    int s2 = sd0[i];
    unsigned u = *(const unsigned*)(xb + (size_t)s2 * 128 + lane * 2);
    float4 wa = *(const float4*)&wl0[i * 8];
    float4 wb = *(const float4*)&wl0[i * 8 + 4];
    f32x2 lod, hid;
    lod[0] = lod[1] = __uint_as_float(u << 16);
    hid[0] = hid[1] = __uint_as_float(u & 0xFFFF0000u);
    f32x2 w01, w23, w45, w67;
    w01[0] = wa.x; w01[1] = wa.y; w23[0] = wa.z; w23[1] = wa.w;
    w45[0] = wb.x; w45[1] = wb.y; w67[0] = wb.z; w67[1] = wb.w;
    aA00 = fma2(w01, lod, aA00); aA01 = fma2(w01, hid, aA01);
    aA10 = fma2(w23, lod, aA10); aA11 = fma2(w23, hid, aA11);
    aA20 = fma2(w45, lod, aA20); aA21 = fma2(w45, hid, aA21);
    aA30 = fma2(w67, lod, aA30); aA31 = fma2(w67, hid, aA31);
  };
  auto stepB = [&](int i) {
    int s2 = sd1[i];
    unsigned u = *(const unsigned*)(xb + (size_t)s2 * 128 + lane * 2);
    float4 wa = *(const float4*)&wl1[i * 8];
    float4 wb = *(const float4*)&wl1[i * 8 + 4];
    f32x2 lod, hid;
    lod[0] = lod[1] = __uint_as_float(u << 16);
    hid[0] = hid[1] = __uint_as_float(u & 0xFFFF0000u);
    f32x2 w01, w23, w45, w67;
    w01[0] = wa.x; w01[1] = wa.y; w23[0] = wa.z; w23[1] = wa.w;
    w45[0] = wb.x; w45[1] = wb.y; w67[0] = wb.z; w67[1] = wb.w;
    aB00 = fma2(w01, lod, aB00); aB01 = fma2(w01, hid, aB01);
    aB10 = fma2(w23, lod, aB10); aB11 = fma2(w23, hid, aB11);
    aB20 = fma2(w45, lod, aB20); aB21 = fma2(w45, hid, aB21);
    aB30 = fma2(w67, lod, aB30); aB31 = fma2(w67, hid, aB31);
  };
  int dmin = min(d0, d1);
  int i = 0;
  for (; i < dmin; ++i) { stepA(i); stepB(i); }
  for (int k = i; k < d0; ++k) stepA(k);
  for (int k = i; k < d1; ++k) stepB(k);
  // scale by 1/z and store
  if (v0) {
    if (d0 > 0) {
      float iz[8];
      #pragma unroll
      for (int h = 0; h < 8; ++h) iz[h] = mz0[h];
      f32x2 s01, s23, s45, s67;
      s01[0] = iz[0]; s01[1] = iz[1]; s23[0] = iz[2]; s23[1] = iz[3];
      s45[0] = iz[4]; s45[1] = iz[5]; s67[0] = iz[6]; s67[1] = iz[7];
      aA00 *= s01; aA01 *= s01; aA10 *= s23; aA11 *= s23;
      aA20 *= s45; aA21 *= s45; aA30 *= s67; aA31 *= s67;
    }
    unsigned short* op = xagg + (size_t)n0 * 1024;
    unsigned pk;
    pk = (unsigned)f2bf(aA00[0]) | ((unsigned)f2bf(aA01[0]) << 16);
    *(unsigned*)(op + 0 * 128 + lane * 2) = pk;
    pk = (unsigned)f2bf(aA00[1]) | ((unsigned)f2bf(aA01[1]) << 16);
    *(unsigned*)(op + 1 * 128 + lane * 2) = pk;
    pk = (unsigned)f2bf(aA10[0]) | ((unsigned)f2bf(aA11[0]) << 16);
    *(unsigned*)(op + 2 * 128 + lane * 2) = pk;
    pk = (unsigned)f2bf(aA10[1]) | ((unsigned)f2bf(aA11[1]) << 16);
    *(unsigned*)(op + 3 * 128 + lane * 2) = pk;
    pk = (unsigned)f2bf(aA20[0]) | ((unsigned)f2bf(aA21[0]) << 16);
    *(unsigned*)(op + 4 * 128 + lane * 2) = pk;
    pk = (unsigned)f2bf(aA20[1]) | ((unsigned)f2bf(aA21[1]) << 16);
    *(unsigned*)(op + 5 * 128 + lane * 2) = pk;
    pk = (unsigned)f2bf(aA30[0]) | ((unsigned)f2bf(aA31[0]) << 16);
    *(unsigned*)(op + 6 * 128 + lane * 2) = pk;
    pk = (unsigned)f2bf(aA30[1]) | ((unsigned)f2bf(aA31[1]) << 16);
    *(unsigned*)(op + 7 * 128 + lane * 2) = pk;
  }
  if (v1) {
    if (d1 > 0) {
      float iz[8];
      #pragma unroll
      for (int h = 0; h < 8; ++h) iz[h] = mz1[h];
      f32x2 s01, s23, s45, s67;
      s01[0] = iz[0]; s01[1] = iz[1]; s23[0] = iz[2]; s23[1] = iz[3];
      s45[0] = iz[4]; s45[1] = iz[5]; s67[0] = iz[6]; s67[1] = iz[7];
      aB00 *= s01; aB01 *= s01; aB10 *= s23; aB11 *= s23;
      aB20 *= s45; aB21 *= s45; aB30 *= s67; aB31 *= s67;
    }
    unsigned short* op = xagg + (size_t)n1 * 1024;
    unsigned pk;
    pk = (unsigned)f2bf(aB00[0]) | ((unsigned)f2bf(aB01[0]) << 16);
    *(unsigned*)(op + 0 * 128 + lane * 2) = pk;
    pk = (unsigned)f2bf(aB00[1]) | ((unsigned)f2bf(aB01[1]) << 16);
    *(unsigned*)(op + 1 * 128 + lane * 2) = pk;
    pk = (unsigned)f2bf(aB10[0]) | ((unsigned)f2bf(aB11[0]) << 16);
    *(unsigned*)(op + 2 * 128 + lane * 2) = pk;
    pk = (unsigned)f2bf(aB10[1]) | ((unsigned)f2bf(aB11[1]) << 16);
    *(unsigned*)(op + 3 * 128 + lane * 2) = pk;
    pk = (unsigned)f2bf(aB20[0]) | ((unsigned)f2bf(aB21[0]) << 16);
    *(unsigned*)(op + 4 * 128 + lane * 2) = pk;
    pk = (unsigned)f2bf(aB20[1]) | ((unsigned)f2bf(aB21[1]) << 16);
    *(unsigned*)(op + 5 * 128 + lane * 2) = pk;
    pk = (unsigned)f2bf(aB30[0]) | ((unsigned)f2bf(aB31[0]) << 16);
    *(unsigned*)(op + 6 * 128 + lane * 2) = pk;
    pk = (unsigned)f2bf(aB30[1]) | ((unsigned)f2bf(aB31[1]) << 16);
    *(unsigned*)(op + 7 * 128 + lane * 2) = pk;
  }
}

// ===== gemm1b: out1e[:, h*64:+64] = elu(xagg[:,h,:] @ W1_h + b1_h), bf16 =====
__global__ __launch_bounds__(256)
void gemm1b_mfma(const unsigned short* __restrict__ A,     // xagg [NN][8][128]
                 const unsigned short* __restrict__ w1t,   // [512][128]
                 const float* __restrict__ bias,           // b1 [512]
                 unsigned short* __restrict__ out) {       // out1e [NN][512]
  __shared__ unsigned short As[128][72];
  __shared__ unsigned short Bs[64][72];
  const int t = threadIdx.x, lane = t & 63, wid = t >> 6;
  const int h = blockIdx.y;
  const int row0 = blockIdx.x * 128;
  const int l15 = lane & 15, kg = lane >> 4;
  f32x4 acc[2][4] = {};
  for (int kk = 0; kk < 128; kk += 64) {
    #pragma unroll
    for (int it = 0; it < 4; ++it) {
      int c = t + it * 256;                 // 1024 chunks A
      int r = c >> 3, kc = (c & 7) * 8;
      uint4 v = make_uint4(0, 0, 0, 0);
      if (row0 + r < NN)
        v = *(const uint4*)(A + (size_t)(row0 + r) * 1024 + h * 128 + kk + kc);
      *(uint4*)&As[r][kc] = v;
    }
    #pragma unroll
    for (int it = 0; it < 2; ++it) {
      int c = t + it * 256;                 // 512 chunks B
      int r = c >> 3, kc = (c & 7) * 8;
      *(uint4*)&Bs[r][kc] = *(const uint4*)(w1t + (size_t)(h * 64 + r) * 128 + kk + kc);
    }
    __syncthreads();
    #pragma unroll
    for (int ks = 0; ks < 2; ++ks) {
      bf16x8 af[2], bfr[4];
      #pragma unroll
      for (int fi = 0; fi < 2; ++fi)
        af[fi] = *(const bf16x8*)&As[wid * 32 + fi * 16 + l15][ks * 32 + kg * 8];
      #pragma unroll
      for (int fj = 0; fj < 4; ++fj)
        bfr[fj] = *(const bf16x8*)&Bs[fj * 16 + l15][ks * 32 + kg * 8];
      #pragma unroll
      for (int fi = 0; fi < 2; ++fi)
        #pragma unroll
        for (int fj = 0; fj < 4; ++fj)
          acc[fi][fj] = __builtin_amdgcn_mfma_f32_16x16x32_bf16(af[fi], bfr[fj], acc[fi][fj], 0, 0, 0);
    }
    __syncthreads();
  }
  float bj[4];
  #pragma unroll
  for (int fj = 0; fj < 4; ++fj) bj[fj] = bias[h * 64 + fj * 16 + l15];
  #pragma unroll
  for (int fi = 0; fi < 2; ++fi) {
    const int rbase = row0 + wid * 32 + fi * 16 + kg * 4;
    #pragma unroll
    for (int r = 0; r < 4; ++r) {
      int row = rbase + r;
      if (row < NN) {
        #pragma unroll
        for (int fj = 0; fj < 4; ++fj)
          out[(size_t)row * 512 + h * 64 + fj * 16 + l15] = f2bf(elu(acc[fi][fj][r] + bj[fj]));
      }
    }
  }
}

// ====== GEMM2 (MFMA): feat2(bf16) = out1e @ W2T^T, fused el2/er2 =============
__global__ __launch_bounds__(256)
void gemm2_mfma(const unsigned short* __restrict__ A,     // out1e [NN][512] bf16
                const unsigned short* __restrict__ w2t,   // [64][512] bf16
                const float* __restrict__ al, const float* __restrict__ ar,
                unsigned short* __restrict__ C,           // feat2 [NN][64] bf16
                float* __restrict__ el, float* __restrict__ er) {
  __shared__ unsigned short As[128][72];
  __shared__ unsigned short Bs[64][72];
  const int t = threadIdx.x, lane = t & 63, wid = t >> 6;
  const int row0 = blockIdx.x * 128;
  const int l15 = lane & 15, kg = lane >> 4;
  f32x4 acc[2][4] = {};
  for (int kk = 0; kk < 512; kk += 64) {
    #pragma unroll
    for (int it = 0; it < 4; ++it) {
      int c = t + it * 256;
      int r = c >> 3, kc = (c & 7) * 8;
      uint4 v = make_uint4(0, 0, 0, 0);
      if (row0 + r < NN) v = *(const uint4*)(A + (size_t)(row0 + r) * 512 + kk + kc);
      *(uint4*)&As[r][kc] = v;
    }
    #pragma unroll
    for (int it = 0; it < 2; ++it) {
      int c = t + it * 256;
      int r = c >> 3, kc = (c & 7) * 8;
      *(uint4*)&Bs[r][kc] = *(const uint4*)(w2t + (size_t)r * 512 + kk + kc);
    }
    __syncthreads();
    #pragma unroll
    for (int ks = 0; ks < 2; ++ks) {
      bf16x8 af[2], bfr[4];
      #pragma unroll
      for (int fi = 0; fi < 2; ++fi)
        af[fi] = *(const bf16x8*)&As[wid * 32 + fi * 16 + l15][ks * 32 + kg * 8];
      #pragma unroll
      for (int fj = 0; fj < 4; ++fj)
        bfr[fj] = *(const bf16x8*)&Bs[fj * 16 + l15][ks * 32 + kg * 8];
      #pragma unroll
      for (int fi = 0; fi < 2; ++fi)
        #pragma unroll
        for (int fj = 0; fj < 4; ++fj)
          acc[fi][fj] = __builtin_amdgcn_mfma_f32_16x16x32_bf16(af[fi], bfr[fj], acc[fi][fj], 0, 0, 0);
    }
    __syncthreads();
  }
  float alf[4], arf[4];
  #pragma unroll
  for (int fj = 0; fj < 4; ++fj) { alf[fj] = al[fj * 16 + l15]; arf[fj] = ar[fj * 16 + l15]; }
  #pragma unroll
  for (int fi = 0; fi < 2; ++fi) {
    float pl[4] = {}, pr[4] = {};
    #pragma unroll
    for (int fj = 0; fj < 4; ++fj)
      #pragma unroll
      for (int r = 0; r < 4; ++r) {
        pl[r] = fmaf(acc[fi][fj][r], alf[fj], pl[r]);
        pr[r] = fmaf(acc[fi][fj][r], arf[fj], pr[r]);
      }
    const int rbase = row0 + wid * 32 + fi * 16 + kg * 4;
    #pragma unroll
    for (int r = 0; r < 4; ++r) {
      int row = rbase + r;
      if (row < NN) {
        #pragma unroll
        for (int fj = 0; fj < 4; ++fj)
          C[(size_t)row * 64 + fj * 16 + l15] = f2bf(acc[fi][fj][r]);
      }
    }
    #pragma unroll
    for (int s = 1; s <= 8; s <<= 1)
      #pragma unroll
      for (int r = 0; r < 4; ++r) {
        pl[r] += __shfl_xor(pl[r], s);
        pr[r] += __shfl_xor(pr[r], s);
      }
    if (l15 == 0) {
      #pragma unroll
      for (int r = 0; r < 4; ++r) {
        int row = rbase + r;
        if (row < NN) { el[row] = pl[r]; er[row] = pr[r]; }
      }
    }
  }
}

// ==== agg2f: single head, 2 nodes per wave, no-max softmax, bf16 feat ========
__global__ __launch_bounds__(256)
void agg2f_kernel(const unsigned short* __restrict__ feat,   // [NN][64] bf16
                  const float* __restrict__ el, const float* __restrict__ er,
                  const int* __restrict__ srcs, const int* __restrict__ rowptr,
                  const float* __restrict__ bias, float* __restrict__ out, int N) {
  __shared__ float wlds[4][2][64];
  __shared__ int slds[4][2][64];
  int wv = threadIdx.x >> 6;
  int lane = threadIdx.x & 63;
  int n0 = blockIdx.x * 8 + wv * 2, n1 = n0 + 1;
  bool v0 = n0 < N, v1 = n1 < N;
  int p00 = 0, d0 = 0, p01 = 0, d1 = 0;
  if (v0) { p00 = rowptr[n0]; d0 = rowptr[n0 + 1] - p00; }
  if (v1) { p01 = rowptr[n1]; d1 = rowptr[n1 + 1] - p01; }
  float* wl0 = wlds[wv][0]; float* wl1 = wlds[wv][1];
  int* sd0 = slds[wv][0];   int* sd1 = slds[wv][1];

  if (d0 > 64 || d1 > 64) {
    // rare fallback: whole-wave per node, with max
    for (int q = 0; q < 2; ++q) {
      int n = q ? n1 : n0;
      if (n >= N) continue;
      int p0 = q ? p01 : p00;
      int deg = q ? d1 : d0;
      float acc = 0.f;
      if (deg > 0) {
        int p1 = p0 + deg;
        float ern = er[n];
        float m = -3.4e38f;
        for (int i = p0 + lane; i < p1; i += 64)
          m = fmaxf(m, lrelu(el[srcs[i]] + ern));
        #pragma unroll
        for (int st = 1; st <= 32; st <<= 1) m = fmaxf(m, __shfl_xor(m, st));
        float z = 0.f;
        for (int i = p0 + lane; i < p1; i += 64)
          z += __expf(lrelu(el[srcs[i]] + ern) - m);
        #pragma unroll
        for (int st = 1; st <= 32; st <<= 1) z += __shfl_xor(z, st);
        float iz = 1.f / z;
        for (int i = p0; i < p1; ++i) {
          int s0 = srcs[i];
          float w = __expf(lrelu(el[s0] + ern) - m) * iz;
          acc = fmaf(bf2f(feat[(size_t)s0 * 64 + lane]), w, acc);
        }
      }
      out[(size_t)n * 64 + lane] = acc + bias[lane];
    }
    return;
  }
  // fast path
  float iz0 = 0.f, iz1 = 0.f;
  if (v0 && d0 > 0) {
    float ern = er[n0];
    float w = 0.f;
    if (lane < d0) {
      int s = srcs[p00 + lane];
      sd0[lane] = s;
      w = __expf(lrelu(el[s] + ern));
    }
    wl0[lane] = w;
    float z = w;
    #pragma unroll
    for (int st = 1; st <= 32; st <<= 1) z += __shfl_xor(z, st);
    iz0 = 1.f / z;
  }
  if (v1 && d1 > 0) {
    float ern = er[n1];
    float w = 0.f;
    if (lane < d1) {
      int s = srcs[p01 + lane];
      sd1[lane] = s;
      w = __expf(lrelu(el[s] + ern));
    }
    wl1[lane] = w;
    float z = w;
    #pragma unroll
    for (int st = 1; st <= 32; st <<= 1) z += __shfl_xor(z, st);
    iz1 = 1.f / z;
  }
  asm volatile("s_waitcnt lgkmcnt(0)" ::: "memory");
  float accA = 0.f, accB = 0.f;
  int dmin = min(d0, d1);
  int i = 0;
  for (; i < dmin; ++i) {
    accA = fmaf(bf2f(feat[(size_t)sd0[i] * 64 + lane]), wl0[i], accA);
    accB = fmaf(bf2f(feat[(size_t)sd1[i] * 64 + lane]), wl1[i], accB);
  }
  for (int k = i; k < d0; ++k)
    accA = fmaf(bf2f(feat[(size_t)sd0[k] * 64 + lane]), wl0[k], accA);
  for (int k = i; k < d1; ++k)
    accB = fmaf(bf2f(feat[(size_t)sd1[k] * 64 + lane]), wl1[k], accB);
  if (v0) out[(size_t)n0 * 64 + lane] = accA * iz0 + bias[lane];
  if (v1) out[(size_t)n1 * 64 + lane] = accB * iz1 + bias[lane];
}

extern "C" void kernel_launch(void* const* d_in, const int* in_sizes, int n_in,
                              void* d_out, int out_size, void* d_ws, size_t ws_size,
                              hipStream_t stream) {
  const float* x   = (const float*)d_in[0];
  const int*   src = (const int*)d_in[1];
  const int*   dst = (const int*)d_in[2];
  const float* W1  = (const float*)d_in[3];
  const float* al1 = (const float*)d_in[4];
  const float* ar1 = (const float*)d_in[5];
  const float* b1  = (const float*)d_in[6];
  const float* W2  = (const float*)d_in[7];
  const float* al2 = (const float*)d_in[8];
  const float* ar2 = (const float*)d_in[9];
  const float* b2  = (const float*)d_in[10];
  float* out = (float*)d_out;

  char* p = (char*)d_ws;
  auto alloc = [&](size_t bytes) { void* r = (void*)p; p += (bytes + 255) & ~(size_t)255; return r; };
  unsigned short* xb    = (unsigned short*)alloc((size_t)NN * 128 * 2);   // 12.8 MB
  unsigned short* w1t   = (unsigned short*)alloc((size_t)512 * 128 * 2);
  unsigned short* w2t   = (unsigned short*)alloc((size_t)64 * 512 * 2);
  unsigned short* walb  = (unsigned short*)alloc((size_t)16 * 128 * 2);
  unsigned short* xagg  = (unsigned short*)alloc((size_t)NN * 1024 * 2);  // 102.4 MB
  unsigned short* out1e = (unsigned short*)alloc((size_t)NN * 512 * 2);   // 51.2 MB
  float* el1   = (float*)alloc((size_t)NN * 8 * 4);
  float* er1   = (float*)alloc((size_t)NN * 8 * 4);
  unsigned short* feat2 = (unsigned short*)alloc((size_t)NN * 64 * 2);    // 6.4 MB bf16
  float* el2   = (float*)alloc((size_t)NN * 4);
  float* er2   = (float*)alloc((size_t)NN * 4);
  int* rowptr  = (int*)alloc((size_t)(NN + 1) * 4);
  int* srcs    = (int*)alloc((size_t)NE * 4);
  int* cnt     = (int*)alloc((size_t)NN * 4);
  int* fill    = (int*)alloc((size_t)NN * 4);
  int* bsum    = (int*)alloc((size_t)128 * 4);
  int* boff    = (int*)alloc((size_t)128 * 4);

  hipMemsetAsync(cnt, 0, (size_t)NN * 4, stream);
  hipMemsetAsync(fill, 0, (size_t)NN * 4, stream);

  // prep (cvt_x + W transposes + walb + hist)
  prep_all_kernel<<<(1700352 + 255) / 256, 256, 0, stream>>>(
      x, xb, W1, W2, al1, ar1, w1t, w2t, walb, dst, cnt);

  // CSR: multiblock scan + scatter
  const int NB = (NN + 511) / 512;   // 98
  scan1_kernel<<<NB, 512, 0, stream>>>(cnt, rowptr, bsum, NN);
  scan2_kernel<<<1, 128, 0, stream>>>(bsum, boff, NB);
  scan3_kernel<<<NB, 512, 0, stream>>>(rowptr, boff, NN);
  scatter_kernel<<<(NE + 255) / 256, 256, 0, stream>>>(dst, src, rowptr, fill, srcs, NE);

  // layer 1 (linearity-reordered)
  eler_kernel<<<(NN + 63) / 64, 256, 0, stream>>>(xb, walb, el1, er1);
  aggx_kernel<<<(NN + 7) / 8, 256, 0, stream>>>(xb, el1, er1, srcs, rowptr, xagg, NN);
  gemm1b_mfma<<<dim3((NN + 127) / 128, 8), 256, 0, stream>>>(xagg, w1t, b1, out1e);

  // layer 2
  gemm2_mfma<<<(NN + 127) / 128, 256, 0, stream>>>(out1e, w2t, al2, ar2, feat2, el2, er2);
  agg2f_kernel<<<(NN + 7) / 8, 256, 0, stream>>>(feat2, el2, er2, srcs, rowptr, b2, out, NN);
}

// Round 19
// 260.091 us; speedup vs baseline: 1.6116x; 1.0513x over previous
//
#include <hip/hip_runtime.h>
#include <cstdint>

// GAT 2-layer: N=50000, E=800000.
// Layer 1 via linearity: aggregate x (256B bf16 rows), then batched per-head
// MFMA GEMM. aggx & agg2f: 2 nodes/wave, no-max softmax. Multiblock CSR scan.
// feat2 bf16. aggx LDS weights stored bf16 (1 b128 read/edge) + setprio.
#define NN 50000
#define NE 800000

typedef short bf16x8 __attribute__((ext_vector_type(8)));
typedef float f32x4 __attribute__((ext_vector_type(4)));
typedef float f32x2 __attribute__((ext_vector_type(2)));

__device__ __forceinline__ float lrelu(float x) { return x > 0.f ? x : 0.2f * x; }
__device__ __forceinline__ float elu(float x) { return x > 0.f ? x : __expf(x) - 1.f; }
__device__ __forceinline__ unsigned short f2bf(float f) {
  unsigned u = __float_as_uint(f);
  unsigned r = (u + 0x7FFFu + ((u >> 16) & 1u)) >> 16;   // RNE
  return (unsigned short)r;
}
__device__ __forceinline__ float bf2f(unsigned short u) {
  return __uint_as_float((unsigned)u << 16);
}
__device__ __forceinline__ f32x2 fma2(f32x2 a, f32x2 b, f32x2 c) {
#if __has_builtin(__builtin_elementwise_fma)
  return __builtin_elementwise_fma(a, b, c);
#else
  f32x2 r; r[0] = fmaf(a[0], b[0], c[0]); r[1] = fmaf(a[1], b[1], c[1]); return r;
#endif
}

// ===================== prep (fused cvt_x + w-transposes + walb + hist) ======
__global__ __launch_bounds__(256)
void prep_all_kernel(const float* __restrict__ x, unsigned short* __restrict__ xb,
                     const float* __restrict__ W1, const float* __restrict__ W2,
                     const float* __restrict__ al, const float* __restrict__ ar,
                     unsigned short* __restrict__ w1t, unsigned short* __restrict__ w2t,
                     unsigned short* __restrict__ walb,
                     const int* __restrict__ dst, int* __restrict__ cnt) {
  int idx = blockIdx.x * 256 + threadIdx.x;
  if (idx < 800000) {                          // cvt_x: 8 elems each
    float4 a = *(const float4*)(x + (size_t)idx * 8);
    float4 b = *(const float4*)(x + (size_t)idx * 8 + 4);
    unsigned short us[8] = { f2bf(a.x), f2bf(a.y), f2bf(a.z), f2bf(a.w),
                             f2bf(b.x), f2bf(b.y), f2bf(b.z), f2bf(b.w) };
    *(uint4*)(xb + (size_t)idx * 8) = *(const uint4*)us;
  } else if (idx < 865536) {                   // W1 -> w1t [512][128]
    int t = idx - 800000;
    int k = t >> 9, c = t & 511;
    w1t[(size_t)c * 128 + k] = f2bf(W1[t]);
  } else if (idx < 898304) {                   // W2 -> w2t [64][512]
    int t = idx - 865536;
    int k = t >> 6, c = t & 63;
    w2t[(size_t)c * 512 + k] = f2bf(W2[t]);
  } else if (idx < 900352) {                   // walb [16][128]
    int t = idx - 898304;
    int k = t >> 4, o = t & 15, h = o & 7;
    const float* a = (o < 8) ? al : ar;
    float s = 0.f;
    #pragma unroll 8
    for (int d = 0; d < 64; ++d)
      s += W1[(size_t)k * 512 + h * 64 + d] * a[h * 64 + d];
    walb[o * 128 + k] = f2bf(s);
  } else if (idx < 1700352) {                  // hist
    int e = idx - 900352;
    atomicAdd(&cnt[dst[e]], 1);
  }
}

// ===== eler: el1/er1 [N,8] = xb @ walb^T via MFMA, 16 nodes/wave ============
__global__ __launch_bounds__(256)
void eler_kernel(const unsigned short* __restrict__ xb,    // [NN][128]
                 const unsigned short* __restrict__ walb,  // [16][128]
                 float* __restrict__ el, float* __restrict__ er) {
  int wv = threadIdx.x >> 6, lane = threadIdx.x & 63;
  int row0 = blockIdx.x * 64 + wv * 16;
  const int l15 = lane & 15, kg = lane >> 4;
  f32x4 c = {0.f, 0.f, 0.f, 0.f};
  #pragma unroll
  for (int ks = 0; ks < 4; ++ks) {
    bf16x8 a = {};
    int row = row0 + l15;
    if (row < NN) a = *(const bf16x8*)(xb + (size_t)row * 128 + ks * 32 + kg * 8);
    bf16x8 b = *(const bf16x8*)(walb + (size_t)l15 * 128 + ks * 32 + kg * 8);
    c = __builtin_amdgcn_mfma_f32_16x16x32_bf16(a, b, c, 0, 0, 0);
  }
  #pragma unroll
  for (int r = 0; r < 4; ++r) {
    int row = row0 + kg * 4 + r;
    if (row < NN) {
      if (l15 < 8) el[(size_t)row * 8 + l15] = c[r];
      else         er[(size_t)row * 8 + (l15 - 8)] = c[r];
    }
  }
}

// ============== multiblock exclusive scan: cnt[NN] -> rowptr =================
__global__ __launch_bounds__(512)
void scan1_kernel(const int* __restrict__ cnt, int* __restrict__ rowptr,
                  int* __restrict__ bsum, int N) {
  __shared__ int s[512];
  int t = threadIdx.x;
  int i = blockIdx.x * 512 + t;
  int v = (i < N) ? cnt[i] : 0;
  s[t] = v;
  __syncthreads();
  #pragma unroll
  for (int d = 1; d < 512; d <<= 1) {
    int u = (t >= d) ? s[t - d] : 0;
    __syncthreads();
    s[t] += u;
    __syncthreads();
  }
  if (i < N) rowptr[i] = s[t] - v;      // local exclusive
  if (t == 511) bsum[blockIdx.x] = s[511];
}

__global__ __launch_bounds__(128)
void scan2_kernel(int* __restrict__ bsum, int* __restrict__ boff, int nb) {
  if (threadIdx.x == 0) {
    int run = 0;
    for (int i = 0; i < nb; ++i) { boff[i] = run; run += bsum[i]; }
  }
}

__global__ __launch_bounds__(512)
void scan3_kernel(int* __restrict__ rowptr, const int* __restrict__ boff, int N) {
  int i = blockIdx.x * 512 + threadIdx.x;
  if (i < N) rowptr[i] += boff[blockIdx.x];
  if (i == 0) rowptr[N] = NE;           // total edge count is a constant
}

__global__ void scatter_kernel(const int* __restrict__ dst, const int* __restrict__ src,
                               const int* __restrict__ rowptr, int* __restrict__ fill,
                               int* __restrict__ srcs, int E) {
  int e = blockIdx.x * 256 + threadIdx.x;
  if (e >= E) return;
  int d = dst[e];
  int pos = atomicAdd(&fill[d], 1);
  srcs[rowptr[d] + pos] = src[e];
}

// ==== aggx: xagg[n,h,:] = sum_e alpha_e,h * xb[src_e,:]; 2 nodes per wave ====
// weights staged in LDS as bf16 (1 b128 read per edge; normalization z is
// computed from the SAME bf16 weights so softmax still sums to 1 in f32).
__global__ __launch_bounds__(256)
void aggx_kernel(const unsigned short* __restrict__ xb,
                 const float* __restrict__ el, const float* __restrict__ er,
                 const int* __restrict__ srcs, const int* __restrict__ rowptr,
                 unsigned short* __restrict__ xagg, int N) {
  __shared__ unsigned short wlds[4][2][64 * 8];   // bf16 weights
  __shared__ int slds[4][2][64];
  __shared__ float mzlds[4][2][8];
  int wv = threadIdx.x >> 6;
  int lane = threadIdx.x & 63;
  const int myh = lane >> 3, j = lane & 7;
  int n0 = blockIdx.x * 8 + wv * 2, n1 = n0 + 1;
  bool v0 = n0 < N, v1 = n1 < N;
  int p00 = 0, d0 = 0, p01 = 0, d1 = 0;
  if (v0) { p00 = rowptr[n0]; d0 = rowptr[n0 + 1] - p00; }
  if (v1) { p01 = rowptr[n1]; d1 = rowptr[n1 + 1] - p01; }
  unsigned short* wl0 = wlds[wv][0]; unsigned short* wl1 = wlds[wv][1];
  int* sd0 = slds[wv][0];   int* sd1 = slds[wv][1];
  float* mz0 = mzlds[wv][0]; float* mz1 = mzlds[wv][1];

  if (d0 > 64 || d1 > 64) {
    // ---- rare fallback: whole-wave per node, 3-pass chunked with max ----
    for (int q = 0; q < 2; ++q) {
      int n = q ? n1 : n0;
      if (n >= N) continue;
      int p0 = q ? p01 : p00;
      int deg = q ? d1 : d0;
      f32x2 a00 = {0.f, 0.f}, a01 = a00, a10 = a00, a11 = a00;
      f32x2 a20 = a00, a21 = a00, a30 = a00, a31 = a00;
      if (deg > 0) {
        int p1 = p0 + deg;
        float er8[8];
        *(float4*)&er8[0] = *(const float4*)(er + (size_t)n * 8);
        *(float4*)&er8[4] = *(const float4*)(er + (size_t)n * 8 + 4);
        float erh = er8[0];
        #pragma unroll
        for (int h = 1; h < 8; ++h) erh = (myh == h) ? er8[h] : erh;
        float m = -3.4e38f;
        for (int i = p0 + j; i < p1; i += 8)
          m = fmaxf(m, lrelu(el[(size_t)srcs[i] * 8 + myh] + erh));
        m = fmaxf(m, __shfl_xor(m, 1));
        m = fmaxf(m, __shfl_xor(m, 2));
        m = fmaxf(m, __shfl_xor(m, 4));
        if (j == 0) mz0[myh] = m;
        asm volatile("s_waitcnt lgkmcnt(0)" ::: "memory");
        float m8[8];
        #pragma unroll
        for (int h = 0; h < 8; ++h) m8[h] = mz0[h];
        float zpart = 0.f;   // accumulated from bf16 weights below
        for (int c0 = p0; c0 < p1; c0 += 64) {
          int cnt = min(64, p1 - c0);
          if (lane < cnt) {
            int s = srcs[c0 + lane];
            sd0[lane] = s;
            float elr[8];
            *(float4*)&elr[0] = *(const float4*)(el + (size_t)s * 8);
            *(float4*)&elr[4] = *(const float4*)(el + (size_t)s * 8 + 4);
            unsigned short us[8];
            #pragma unroll
            for (int h = 0; h < 8; ++h)
              us[h] = f2bf(__expf(lrelu(elr[h] + er8[h]) - m8[h]));
            *(uint4*)&wl0[lane * 8] = *(const uint4*)us;
          }
          asm volatile("s_waitcnt lgkmcnt(0)" ::: "memory");
          // z partial for head myh over this chunk (8 strided slots)
          for (int t2 = j; t2 < cnt; t2 += 8)
            zpart += bf2f(wl0[t2 * 8 + myh]);
          for (int i = 0; i < cnt; ++i) {
            int s2 = sd0[i];
            unsigned u = *(const unsigned*)(xb + (size_t)s2 * 128 + lane * 2);
            uint4 wq = *(const uint4*)&wl0[i * 8];
            f32x2 lod, hid;
            lod[0] = lod[1] = __uint_as_float(u << 16);
            hid[0] = hid[1] = __uint_as_float(u & 0xFFFF0000u);
            f32x2 w01, w23, w45, w67;
            w01[0] = __uint_as_float(wq.x << 16); w01[1] = __uint_as_float(wq.x & 0xFFFF0000u);
            w23[0] = __uint_as_float(wq.y << 16); w23[1] = __uint_as_float(wq.y & 0xFFFF0000u);
            w45[0] = __uint_as_float(wq.z << 16); w45[1] = __uint_as_float(wq.z & 0xFFFF0000u);
            w67[0] = __uint_as_float(wq.w << 16); w67[1] = __uint_as_float(wq.w & 0xFFFF0000u);
            a00 = fma2(w01, lod, a00); a01 = fma2(w01, hid, a01);
            a10 = fma2(w23, lod, a10); a11 = fma2(w23, hid, a11);
            a20 = fma2(w45, lod, a20); a21 = fma2(w45, hid, a21);
            a30 = fma2(w67, lod, a30); a31 = fma2(w67, hid, a31);
          }
          asm volatile("s_waitcnt lgkmcnt(0)" ::: "memory");
        }
        zpart += __shfl_xor(zpart, 1);
        zpart += __shfl_xor(zpart, 2);
        zpart += __shfl_xor(zpart, 4);
        if (j == 0) mz1[myh] = 1.f / zpart;
        asm volatile("s_waitcnt lgkmcnt(0)" ::: "memory");
        float iz8[8];
        #pragma unroll
        for (int h = 0; h < 8; ++h) iz8[h] = mz1[h];
        f32x2 s01, s23, s45, s67;
        s01[0] = iz8[0]; s01[1] = iz8[1]; s23[0] = iz8[2]; s23[1] = iz8[3];
        s45[0] = iz8[4]; s45[1] = iz8[5]; s67[0] = iz8[6]; s67[1] = iz8[7];
        a00 *= s01; a01 *= s01; a10 *= s23; a11 *= s23;
        a20 *= s45; a21 *= s45; a30 *= s67; a31 *= s67;
      }
      unsigned short* op = xagg + (size_t)n * 1024;
      unsigned pk;
      pk = (unsigned)f2bf(a00[0]) | ((unsigned)f2bf(a01[0]) << 16);
      *(unsigned*)(op + 0 * 128 + lane * 2) = pk;
      pk = (unsigned)f2bf(a00[1]) | ((unsigned)f2bf(a01[1]) << 16);
      *(unsigned*)(op + 1 * 128 + lane * 2) = pk;
      pk = (unsigned)f2bf(a10[0]) | ((unsigned)f2bf(a11[0]) << 16);
      *(unsigned*)(op + 2 * 128 + lane * 2) = pk;
      pk = (unsigned)f2bf(a10[1]) | ((unsigned)f2bf(a11[1]) << 16);
      *(unsigned*)(op + 3 * 128 + lane * 2) = pk;
      pk = (unsigned)f2bf(a20[0]) | ((unsigned)f2bf(a21[0]) << 16);
      *(unsigned*)(op + 4 * 128 + lane * 2) = pk;
      pk = (unsigned)f2bf(a20[1]) | ((unsigned)f2bf(a21[1]) << 16);
      *(unsigned*)(op + 5 * 128 + lane * 2) = pk;
      pk = (unsigned)f2bf(a30[0]) | ((unsigned)f2bf(a31[0]) << 16);
      *(unsigned*)(op + 6 * 128 + lane * 2) = pk;
      pk = (unsigned)f2bf(a30[1]) | ((unsigned)f2bf(a31[1]) << 16);
      *(unsigned*)(op + 7 * 128 + lane * 2) = pk;
    }
    return;
  }

  // ---- fast path: no-max softmax, 2 nodes interleaved, bf16 weights ----
  if (v0 && d0 > 0) {
    float er8[8];
    *(float4*)&er8[0] = *(const float4*)(er + (size_t)n0 * 8);
    *(float4*)&er8[4] = *(const float4*)(er + (size_t)n0 * 8 + 4);
    unsigned short us[8] = {0, 0, 0, 0, 0, 0, 0, 0};
    if (lane < d0) {
      int s = srcs[p00 + lane];
      sd0[lane] = s;
      float elr[8];
      *(float4*)&elr[0] = *(const float4*)(el + (size_t)s * 8);
      *(float4*)&elr[4] = *(const float4*)(el + (size_t)s * 8 + 4);
      #pragma unroll
      for (int h = 0; h < 8; ++h) us[h] = f2bf(__expf(lrelu(elr[h] + er8[h])));
    }
    *(uint4*)&wl0[lane * 8] = *(const uint4*)us;
  }
  if (v1 && d1 > 0) {
    float er8[8];
    *(float4*)&er8[0] = *(const float4*)(er + (size_t)n1 * 8);
    *(float4*)&er8[4] = *(const float4*)(er + (size_t)n1 * 8 + 4);
    unsigned short us[8] = {0, 0, 0, 0, 0, 0, 0, 0};
    if (lane < d1) {
      int s = srcs[p01 + lane];
      sd1[lane] = s;
      float elr[8];
      *(float4*)&elr[0] = *(const float4*)(el + (size_t)s * 8);
      *(float4*)&elr[4] = *(const float4*)(el + (size_t)s * 8 + 4);
      #pragma unroll
      for (int h = 0; h < 8; ++h) us[h] = f2bf(__expf(lrelu(elr[h] + er8[h])));
    }
    *(uint4*)&wl1[lane * 8] = *(const uint4*)us;
  }
  asm volatile("s_waitcnt lgkmcnt(0)" ::: "memory");
  // z-reduce per node: roles (myh, j): 8 strided bf16 reads + 3 shfl
  if (v0 && d0 > 0) {
    float z = 0.f;
    #pragma unroll
    for (int t2 = 0; t2 < 8; ++t2) z += bf2f(wl0[(t2 * 8 + j) * 8 + myh]);
    z += __shfl_xor(z, 1); z += __shfl_xor(z, 2); z += __shfl_xor(z, 4);
    if (j == 0) mz0[myh] = 1.f / z;
  }
  if (v1 && d1 > 0) {
    float z = 0.f;
    #pragma unroll
    for (int t2 = 0; t2 < 8; ++t2) z += bf2f(wl1[(t2 * 8 + j) * 8 + myh]);
    z += __shfl_xor(z, 1); z += __shfl_xor(z, 2); z += __shfl_xor(z, 4);
    if (j == 0) mz1[myh] = 1.f / z;
  }
  asm volatile("s_waitcnt lgkmcnt(0)" ::: "memory");
  // interleaved aggregation: two independent chains
  f32x2 aA00 = {0.f, 0.f}, aA01 = aA00, aA10 = aA00, aA11 = aA00;
  f32x2 aA20 = aA00, aA21 = aA00, aA30 = aA00, aA31 = aA00;
  f32x2 aB00 = aA00, aB01 = aA00, aB10 = aA00, aB11 = aA00;
  f32x2 aB20 = aA00, aB21 = aA00, aB30 = aA00, aB31 = aA00;
  auto stepA = [&](int i) {
    int s2 = sd0[i];
    unsigned u = *(const unsigned*)(xb + (size_t)s2 * 128 + lane * 2);
    uint4 wq = *(const uint4*)&wl0[i * 8];
    f32x2 lod, hid;
    lod[0] = lod[1] = __uint_as_float(u << 16);
    hid[0] = hid[1] = __uint_as_float(u & 0xFFFF0000u);
    f32x2 w01, w23, w45, w67;
    w01[0] = __uint_as_float(wq.x << 16); w01[1] = __uint_as_float(wq.x & 0xFFFF0000u);
    w23[0] = __uint_as_float(wq.y << 16); w23[1] = __uint_as_float(wq.y & 0xFFFF0000u);
    w45[0] = __uint_as_float(wq.z << 16); w45[1] = __uint_as_float(wq.z & 0xFFFF0000u);
    w67[0] = __uint_as_float(wq.w << 16); w67[1] = __uint_as_float(wq.w & 0xFFFF0000u);
    aA00 = fma2(w01, lod, aA00); aA01 = fma2(w01, hid, aA01);
    aA10 = fma2(w23, lod, aA10); aA11 = fma2(w23, hid, aA11);
    aA20 = fma2(w45, lod, aA20); aA21 = fma2(w45, hid, aA21);
    aA30 = fma2(w67, lod, aA30); aA31 = fma2(w67, hid, aA31);
  };
  auto stepB = [&](int i) {
    int s2 = sd1[i];
    unsigned u = *(const unsigned*)(xb + (size_t)s2 * 128 + lane * 2);
    uint4 wq = *(const uint4*)&wl1[i * 8];
    f32x2 lod, hid;
    lod[0] = lod[1] = __uint_as_float(u << 16);
    hid[0] = hid[1] = __uint_as_float(u & 0xFFFF0000u);
    f32x2 w01, w23, w45, w67;
    w01[0] = __uint_as_float(wq.x << 16); w01[1] = __uint_as_float(wq.x & 0xFFFF0000u);
    w23[0] = __uint_as_float(wq.y << 16); w23[1] = __uint_as_float(wq.y & 0xFFFF0000u);
    w45[0] = __uint_as_float(wq.z << 16); w45[1] = __uint_as_float(wq.z & 0xFFFF0000u);
    w67[0] = __uint_as_float(wq.w << 16); w67[1] = __uint_as_float(wq.w & 0xFFFF0000u);
    aB00 = fma2(w01, lod, aB00); aB01 = fma2(w01, hid, aB01);
    aB10 = fma2(w23, lod, aB10); aB11 = fma2(w23, hid, aB11);
    aB20 = fma2(w45, lod, aB20); aB21 = fma2(w45, hid, aB21);
    aB30 = fma2(w67, lod, aB30); aB31 = fma2(w67, hid, aB31);
  };
  __builtin_amdgcn_s_setprio(1);
  int dmin = min(d0, d1);
  int i = 0;
  for (; i < dmin; ++i) { stepA(i); stepB(i); }
  for (int k = i; k < d0; ++k) stepA(k);
  for (int k = i; k < d1; ++k) stepB(k);
  __builtin_amdgcn_s_setprio(0);
  // scale by 1/z and store
  if (v0) {
    if (d0 > 0) {
      float iz[8];
      #pragma unroll
      for (int h = 0; h < 8; ++h) iz[h] = mz0[h];
      f32x2 s01, s23, s45, s67;
      s01[0] = iz[0]; s01[1] = iz[1]; s23[0] = iz[2]; s23[1] = iz[3];
      s45[0] = iz[4]; s45[1] = iz[5]; s67[0] = iz[6]; s67[1] = iz[7];
      aA00 *= s01; aA01 *= s01; aA10 *= s23; aA11 *= s23;
      aA20 *= s45; aA21 *= s45; aA30 *= s67; aA31 *= s67;
    }
    unsigned short* op = xagg + (size_t)n0 * 1024;
    unsigned pk;
    pk = (unsigned)f2bf(aA00[0]) | ((unsigned)f2bf(aA01[0]) << 16);
    *(unsigned*)(op + 0 * 128 + lane * 2) = pk;
    pk = (unsigned)f2bf(aA00[1]) | ((unsigned)f2bf(aA01[1]) << 16);
    *(unsigned*)(op + 1 * 128 + lane * 2) = pk;
    pk = (unsigned)f2bf(aA10[0]) | ((unsigned)f2bf(aA11[0]) << 16);
    *(unsigned*)(op + 2 * 128 + lane * 2) = pk;
    pk = (unsigned)f2bf(aA10[1]) | ((unsigned)f2bf(aA11[1]) << 16);
    *(unsigned*)(op + 3 * 128 + lane * 2) = pk;
    pk = (unsigned)f2bf(aA20[0]) | ((unsigned)f2bf(aA21[0]) << 16);
    *(unsigned*)(op + 4 * 128 + lane * 2) = pk;
    pk = (unsigned)f2bf(aA20[1]) | ((unsigned)f2bf(aA21[1]) << 16);
    *(unsigned*)(op + 5 * 128 + lane * 2) = pk;
    pk = (unsigned)f2bf(aA30[0]) | ((unsigned)f2bf(aA31[0]) << 16);
    *(unsigned*)(op + 6 * 128 + lane * 2) = pk;
    pk = (unsigned)f2bf(aA30[1]) | ((unsigned)f2bf(aA31[1]) << 16);
    *(unsigned*)(op + 7 * 128 + lane * 2) = pk;
  }
  if (v1) {
    if (d1 > 0) {
      float iz[8];
      #pragma unroll
      for (int h = 0; h < 8; ++h) iz[h] = mz1[h];
      f32x2 s01, s23, s45, s67;
      s01[0] = iz[0]; s01[1] = iz[1]; s23[0] = iz[2]; s23[1] = iz[3];
      s45[0] = iz[4]; s45[1] = iz[5]; s67[0] = iz[6]; s67[1] = iz[7];
      aB00 *= s01; aB01 *= s01; aB10 *= s23; aB11 *= s23;
      aB20 *= s45; aB21 *= s45; aB30 *= s67; aB31 *= s67;
    }
    unsigned short* op = xagg + (size_t)n1 * 1024;
    unsigned pk;
    pk = (unsigned)f2bf(aB00[0]) | ((unsigned)f2bf(aB01[0]) << 16);
    *(unsigned*)(op + 0 * 128 + lane * 2) = pk;
    pk = (unsigned)f2bf(aB00[1]) | ((unsigned)f2bf(aB01[1]) << 16);
    *(unsigned*)(op + 1 * 128 + lane * 2) = pk;
    pk = (unsigned)f2bf(aB10[0]) | ((unsigned)f2bf(aB11[0]) << 16);
    *(unsigned*)(op + 2 * 128 + lane * 2) = pk;
    pk = (unsigned)f2bf(aB10[1]) | ((unsigned)f2bf(aB11[1]) << 16);
    *(unsigned*)(op + 3 * 128 + lane * 2) = pk;
    pk = (unsigned)f2bf(aB20[0]) | ((unsigned)f2bf(aB21[0]) << 16);
    *(unsigned*)(op + 4 * 128 + lane * 2) = pk;
    pk = (unsigned)f2bf(aB20[1]) | ((unsigned)f2bf(aB21[1]) << 16);
    *(unsigned*)(op + 5 * 128 + lane * 2) = pk;
    pk = (unsigned)f2bf(aB30[0]) | ((unsigned)f2bf(aB31[0]) << 16);
    *(unsigned*)(op + 6 * 128 + lane * 2) = pk;
    pk = (unsigned)f2bf(aB30[1]) | ((unsigned)f2bf(aB31[1]) << 16);
    *(unsigned*)(op + 7 * 128 + lane * 2) = pk;
  }
}

// ===== gemm1b: out1e[:, h*64:+64] = elu(xagg[:,h,:] @ W1_h + b1_h), bf16 =====
__global__ __launch_bounds__(256)
void gemm1b_mfma(const unsigned short* __restrict__ A,     // xagg [NN][8][128]
                 const unsigned short* __restrict__ w1t,   // [512][128]
                 const float* __restrict__ bias,           // b1 [512]
                 unsigned short* __restrict__ out) {       // out1e [NN][512]
  __shared__ unsigned short As[128][72];
  __shared__ unsigned short Bs[64][72];
  const int t = threadIdx.x, lane = t & 63, wid = t >> 6;
  const int h = blockIdx.y;
  const int row0 = blockIdx.x * 128;
  const int l15 = lane & 15, kg = lane >> 4;
  f32x4 acc[2][4] = {};
  for (int kk = 0; kk < 128; kk += 64) {
    #pragma unroll
    for (int it = 0; it < 4; ++it) {
      int c = t + it * 256;                 // 1024 chunks A
      int r = c >> 3, kc = (c & 7) * 8;
      uint4 v = make_uint4(0, 0, 0, 0);
      if (row0 + r < NN)
        v = *(const uint4*)(A + (size_t)(row0 + r) * 1024 + h * 128 + kk + kc);
      *(uint4*)&As[r][kc] = v;
    }
    #pragma unroll
    for (int it = 0; it < 2; ++it) {
      int c = t + it * 256;                 // 512 chunks B
      int r = c >> 3, kc = (c & 7) * 8;
      *(uint4*)&Bs[r][kc] = *(const uint4*)(w1t + (size_t)(h * 64 + r) * 128 + kk + kc);
    }
    __syncthreads();
    #pragma unroll
    for (int ks = 0; ks < 2; ++ks) {
      bf16x8 af[2], bfr[4];
      #pragma unroll
      for (int fi = 0; fi < 2; ++fi)
        af[fi] = *(const bf16x8*)&As[wid * 32 + fi * 16 + l15][ks * 32 + kg * 8];
      #pragma unroll
      for (int fj = 0; fj < 4; ++fj)
        bfr[fj] = *(const bf16x8*)&Bs[fj * 16 + l15][ks * 32 + kg * 8];
      #pragma unroll
      for (int fi = 0; fi < 2; ++fi)
        #pragma unroll
        for (int fj = 0; fj < 4; ++fj)
          acc[fi][fj] = __builtin_amdgcn_mfma_f32_16x16x32_bf16(af[fi], bfr[fj], acc[fi][fj], 0, 0, 0);
    }
    __syncthreads();
  }
  float bj[4];
  #pragma unroll
  for (int fj = 0; fj < 4; ++fj) bj[fj] = bias[h * 64 + fj * 16 + l15];
  #pragma unroll
  for (int fi = 0; fi < 2; ++fi) {
    const int rbase = row0 + wid * 32 + fi * 16 + kg * 4;
    #pragma unroll
    for (int r = 0; r < 4; ++r) {
      int row = rbase + r;
      if (row < NN) {
        #pragma unroll
        for (int fj = 0; fj < 4; ++fj)
          out[(size_t)row * 512 + h * 64 + fj * 16 + l15] = f2bf(elu(acc[fi][fj][r] + bj[fj]));
      }
    }
  }
}

// ====== GEMM2 (MFMA): feat2(bf16) = out1e @ W2T^T, fused el2/er2 =============
__global__ __launch_bounds__(256)
void gemm2_mfma(const unsigned short* __restrict__ A,     // out1e [NN][512] bf16
                const unsigned short* __restrict__ w2t,   // [64][512] bf16
                const float* __restrict__ al, const float* __restrict__ ar,
                unsigned short* __restrict__ C,           // feat2 [NN][64] bf16
                float* __restrict__ el, float* __restrict__ er) {
  __shared__ unsigned short As[128][72];
  __shared__ unsigned short Bs[64][72];
  const int t = threadIdx.x, lane = t & 63, wid = t >> 6;
  const int row0 = blockIdx.x * 128;
  const int l15 = lane & 15, kg = lane >> 4;
  f32x4 acc[2][4] = {};
  for (int kk = 0; kk < 512; kk += 64) {
    #pragma unroll
    for (int it = 0; it < 4; ++it) {
      int c = t + it * 256;
      int r = c >> 3, kc = (c & 7) * 8;
      uint4 v = make_uint4(0, 0, 0, 0);
      if (row0 + r < NN) v = *(const uint4*)(A + (size_t)(row0 + r) * 512 + kk + kc);
      *(uint4*)&As[r][kc] = v;
    }
    #pragma unroll
    for (int it = 0; it < 2; ++it) {
      int c = t + it * 256;
      int r = c >> 3, kc = (c & 7) * 8;
      *(uint4*)&Bs[r][kc] = *(const uint4*)(w2t + (size_t)r * 512 + kk + kc);
    }
    __syncthreads();
    #pragma unroll
    for (int ks = 0; ks < 2; ++ks) {
      bf16x8 af[2], bfr[4];
      #pragma unroll
      for (int fi = 0; fi < 2; ++fi)
        af[fi] = *(const bf16x8*)&As[wid * 32 + fi * 16 + l15][ks * 32 + kg * 8];
      #pragma unroll
      for (int fj = 0; fj < 4; ++fj)
        bfr[fj] = *(const bf16x8*)&Bs[fj * 16 + l15][ks * 32 + kg * 8];
      #pragma unroll
      for (int fi = 0; fi < 2; ++fi)
        #pragma unroll
        for (int fj = 0; fj < 4; ++fj)
          acc[fi][fj] = __builtin_amdgcn_mfma_f32_16x16x32_bf16(af[fi], bfr[fj], acc[fi][fj], 0, 0, 0);
    }
    __syncthreads();
  }
  float alf[4], arf[4];
  #pragma unroll
  for (int fj = 0; fj < 4; ++fj) { alf[fj] = al[fj * 16 + l15]; arf[fj] = ar[fj * 16 + l15]; }
  #pragma unroll
  for (int fi = 0; fi < 2; ++fi) {
    float pl[4] = {}, pr[4] = {};
    #pragma unroll
    for (int fj = 0; fj < 4; ++fj)
      #pragma unroll
      for (int r = 0; r < 4; ++r) {
        pl[r] = fmaf(acc[fi][fj][r], alf[fj], pl[r]);
        pr[r] = fmaf(acc[fi][fj][r], arf[fj], pr[r]);
      }
    const int rbase = row0 + wid * 32 + fi * 16 + kg * 4;
    #pragma unroll
    for (int r = 0; r < 4; ++r) {
      int row = rbase + r;
      if (row < NN) {
        #pragma unroll
        for (int fj = 0; fj < 4; ++fj)
          C[(size_t)row * 64 + fj * 16 + l15] = f2bf(acc[fi][fj][r]);
      }
    }
    #pragma unroll
    for (int s = 1; s <= 8; s <<= 1)
      #pragma unroll
      for (int r = 0; r < 4; ++r) {
        pl[r] += __shfl_xor(pl[r], s);
        pr[r] += __shfl_xor(pr[r], s);
      }
    if (l15 == 0) {
      #pragma unroll
      for (int r = 0; r < 4; ++r) {
        int row = rbase + r;
        if (row < NN) { el[row] = pl[r]; er[row] = pr[r]; }
      }
    }
  }
}

// ==== agg2f: single head, 2 nodes per wave, no-max softmax, bf16 feat ========
__global__ __launch_bounds__(256)
void agg2f_kernel(const unsigned short* __restrict__ feat,   // [NN][64] bf16
                  const float* __restrict__ el, const float* __restrict__ er,
                  const int* __restrict__ srcs, const int* __restrict__ rowptr,
                  const float* __restrict__ bias, float* __restrict__ out, int N) {
  __shared__ float wlds[4][2][64];
  __shared__ int slds[4][2][64];
  int wv = threadIdx.x >> 6;
  int lane = threadIdx.x & 63;
  int n0 = blockIdx.x * 8 + wv * 2, n1 = n0 + 1;
  bool v0 = n0 < N, v1 = n1 < N;
  int p00 = 0, d0 = 0, p01 = 0, d1 = 0;
  if (v0) { p00 = rowptr[n0]; d0 = rowptr[n0 + 1] - p00; }
  if (v1) { p01 = rowptr[n1]; d1 = rowptr[n1 + 1] - p01; }
  float* wl0 = wlds[wv][0]; float* wl1 = wlds[wv][1];
  int* sd0 = slds[wv][0];   int* sd1 = slds[wv][1];

  if (d0 > 64 || d1 > 64) {
    // rare fallback: whole-wave per node, with max
    for (int q = 0; q < 2; ++q) {
      int n = q ? n1 : n0;
      if (n >= N) continue;
      int p0 = q ? p01 : p00;
      int deg = q ? d1 : d0;
      float acc = 0.f;
      if (deg > 0) {
        int p1 = p0 + deg;
        float ern = er[n];
        float m = -3.4e38f;
        for (int i = p0 + lane; i < p1; i += 64)
          m = fmaxf(m, lrelu(el[srcs[i]] + ern));
        #pragma unroll
        for (int st = 1; st <= 32; st <<= 1) m = fmaxf(m, __shfl_xor(m, st));
        float z = 0.f;
        for (int i = p0 + lane; i < p1; i += 64)
          z += __expf(lrelu(el[srcs[i]] + ern) - m);
        #pragma unroll
        for (int st = 1; st <= 32; st <<= 1) z += __shfl_xor(z, st);
        float iz = 1.f / z;
        for (int i = p0; i < p1; ++i) {
          int s0 = srcs[i];
          float w = __expf(lrelu(el[s0] + ern) - m) * iz;
          acc = fmaf(bf2f(feat[(size_t)s0 * 64 + lane]), w, acc);
        }
      }
      out[(size_t)n * 64 + lane] = acc + bias[lane];
    }
    return;
  }
  // fast path
  float iz0 = 0.f, iz1 = 0.f;
  if (v0 && d0 > 0) {
    float ern = er[n0];
    float w = 0.f;
    if (lane < d0) {
      int s = srcs[p00 + lane];
      sd0[lane] = s;
      w = __expf(lrelu(el[s] + ern));
    }
    wl0[lane] = w;
    float z = w;
    #pragma unroll
    for (int st = 1; st <= 32; st <<= 1) z += __shfl_xor(z, st);
    iz0 = 1.f / z;
  }
  if (v1 && d1 > 0) {
    float ern = er[n1];
    float w = 0.f;
    if (lane < d1) {
      int s = srcs[p01 + lane];
      sd1[lane] = s;
      w = __expf(lrelu(el[s] + ern));
    }
    wl1[lane] = w;
    float z = w;
    #pragma unroll
    for (int st = 1; st <= 32; st <<= 1) z += __shfl_xor(z, st);
    iz1 = 1.f / z;
  }
  asm volatile("s_waitcnt lgkmcnt(0)" ::: "memory");
  float accA = 0.f, accB = 0.f;
  __builtin_amdgcn_s_setprio(1);
  int dmin = min(d0, d1);
  int i = 0;
  for (; i < dmin; ++i) {
    accA = fmaf(bf2f(feat[(size_t)sd0[i] * 64 + lane]), wl0[i], accA);
    accB = fmaf(bf2f(feat[(size_t)sd1[i] * 64 + lane]), wl1[i], accB);
  }
  for (int k = i; k < d0; ++k)
    accA = fmaf(bf2f(feat[(size_t)sd0[k] * 64 + lane]), wl0[k], accA);
  for (int k = i; k < d1; ++k)
    accB = fmaf(bf2f(feat[(size_t)sd1[k] * 64 + lane]), wl1[k], accB);
  __builtin_amdgcn_s_setprio(0);
  if (v0) out[(size_t)n0 * 64 + lane] = accA * iz0 + bias[lane];
  if (v1) out[(size_t)n1 * 64 + lane] = accB * iz1 + bias[lane];
}

extern "C" void kernel_launch(void* const* d_in, const int* in_sizes, int n_in,
                              void* d_out, int out_size, void* d_ws, size_t ws_size,
                              hipStream_t stream) {
  const float* x   = (const float*)d_in[0];
  const int*   src = (const int*)d_in[1];
  const int*   dst = (const int*)d_in[2];
  const float* W1  = (const float*)d_in[3];
  const float* al1 = (const float*)d_in[4];
  const float* ar1 = (const float*)d_in[5];
  const float* b1  = (const float*)d_in[6];
  const float* W2  = (const float*)d_in[7];
  const float* al2 = (const float*)d_in[8];
  const float* ar2 = (const float*)d_in[9];
  const float* b2  = (const float*)d_in[10];
  float* out = (float*)d_out;

  char* p = (char*)d_ws;
  auto alloc = [&](size_t bytes) { void* r = (void*)p; p += (bytes + 255) & ~(size_t)255; return r; };
  unsigned short* xb    = (unsigned short*)alloc((size_t)NN * 128 * 2);   // 12.8 MB
  unsigned short* w1t   = (unsigned short*)alloc((size_t)512 * 128 * 2);
  unsigned short* w2t   = (unsigned short*)alloc((size_t)64 * 512 * 2);
  unsigned short* walb  = (unsigned short*)alloc((size_t)16 * 128 * 2);
  unsigned short* xagg  = (unsigned short*)alloc((size_t)NN * 1024 * 2);  // 102.4 MB
  unsigned short* out1e = (unsigned short*)alloc((size_t)NN * 512 * 2);   // 51.2 MB
  float* el1   = (float*)alloc((size_t)NN * 8 * 4);
  float* er1   = (float*)alloc((size_t)NN * 8 * 4);
  unsigned short* feat2 = (unsigned short*)alloc((size_t)NN * 64 * 2);    // 6.4 MB bf16
  float* el2   = (float*)alloc((size_t)NN * 4);
  float* er2   = (float*)alloc((size_t)NN * 4);
  int* rowptr  = (int*)alloc((size_t)(NN + 1) * 4);
  int* srcs    = (int*)alloc((size_t)NE * 4);
  int* cnt     = (int*)alloc((size_t)NN * 4);
  int* fill    = (int*)alloc((size_t)NN * 4);
  int* bsum    = (int*)alloc((size_t)128 * 4);
  int* boff    = (int*)alloc((size_t)128 * 4);

  hipMemsetAsync(cnt, 0, (size_t)NN * 4, stream);
  hipMemsetAsync(fill, 0, (size_t)NN * 4, stream);

  // prep (cvt_x + W transposes + walb + hist)
  prep_all_kernel<<<(1700352 + 255) / 256, 256, 0, stream>>>(
      x, xb, W1, W2, al1, ar1, w1t, w2t, walb, dst, cnt);

  // CSR: multiblock scan + scatter
  const int NB = (NN + 511) / 512;   // 98
  scan1_kernel<<<NB, 512, 0, stream>>>(cnt, rowptr, bsum, NN);
  scan2_kernel<<<1, 128, 0, stream>>>(bsum, boff, NB);
  scan3_kernel<<<NB, 512, 0, stream>>>(rowptr, boff, NN);
  scatter_kernel<<<(NE + 255) / 256, 256, 0, stream>>>(dst, src, rowptr, fill, srcs, NE);

  // layer 1 (linearity-reordered)
  eler_kernel<<<(NN + 63) / 64, 256, 0, stream>>>(xb, walb, el1, er1);
  aggx_kernel<<<(NN + 7) / 8, 256, 0, stream>>>(xb, el1, er1, srcs, rowptr, xagg, NN);
  gemm1b_mfma<<<dim3((NN + 127) / 128, 8), 256, 0, stream>>>(xagg, w1t, b1, out1e);

  // layer 2
  gemm2_mfma<<<(NN + 127) / 128, 256, 0, stream>>>(out1e, w2t, al2, ar2, feat2, el2, er2);
  agg2f_kernel<<<(NN + 7) / 8, 256, 0, stream>>>(feat2, el2, er2, srcs, rowptr, b2, out, NN);
}